// Round 10
// baseline (1394.820 us; speedup 1.0000x reference)
//
#include <hip/hip_runtime.h>
#include <math.h>

#define BB 64
#define HH 1024
#define VV 32000
#define TT 13
#define QS 8000            // VV/4 per quarter
#define BKL 128            // K-tile for staged logits GEMM

typedef float f32x4 __attribute__((ext_vector_type(4)));
typedef __bf16 bf16x8 __attribute__((ext_vector_type(8)));

__device__ __forceinline__ unsigned short f2bf(float f) {   // RNE
  unsigned u = __float_as_uint(f);
  u = (u + 0x7fffu + ((u >> 16) & 1u)) >> 16;
  return (unsigned short)u;
}
__device__ __forceinline__ float bf2f(unsigned short s) {
  return __uint_as_float(((unsigned)s) << 16);
}

// async global->LDS, 16B per lane; LDS dest = wave-uniform base + lane*16
__device__ __forceinline__ void gld16(const void* g, void* l) {
  __builtin_amdgcn_global_load_lds(
      (const __attribute__((address_space(1))) unsigned int*)g,
      (__attribute__((address_space(3))) unsigned int*)l, 16, 0, 0);
}

// ---------------- init: h0/x0 + splits ----------------
__global__ __launch_bounds__(1024) void k_init(
    const float* __restrict__ enc, const float* __restrict__ emb,
    float* __restrict__ hrm, unsigned short* __restrict__ hhi,
    unsigned short* __restrict__ hlo, unsigned short* __restrict__ xhi,
    unsigned short* __restrict__ xlo) {
  const int g = blockIdx.x * 1024 + threadIdx.x;
  const float h = enc[g];
  hrm[g] = h;
  const unsigned short h16 = f2bf(h);
  hhi[g] = h16;
  hlo[g] = f2bf(h - bf2f(h16));
  float e = emb[threadIdx.x];
  e = e > 0.f ? e : 0.f;
  const unsigned short e16 = f2bf(e);
  xhi[g] = e16;
  xlo[g] = f2bf(e - bf2f(e16));
}

// ---------------- one-time w_out -> bf16 ----------------
__global__ __launch_bounds__(256) void k_wconv(const float* __restrict__ w,
                                               unsigned short* __restrict__ o) {
  const int n4 = VV * HH / 4;
  for (int i = blockIdx.x * 256 + threadIdx.x; i < n4; i += gridDim.x * 256) {
    const f32x4 v = ((const f32x4*)w)[i];
    ushort4 u;
    u.x = f2bf(v[0]); u.y = f2bf(v[1]); u.z = f2bf(v[2]); u.w = f2bf(v[3]);
    ((ushort4*)o)[i] = u;
  }
}

// ---------------- one-time wih/whh -> bf16 hi/lo split ----------------
__global__ __launch_bounds__(256) void k_wconv2(
    const float* __restrict__ wih, const float* __restrict__ whh,
    unsigned short* __restrict__ ghi, unsigned short* __restrict__ glo) {
  const int n4 = 6 * HH * HH / 4;
  for (int i = blockIdx.x * 256 + threadIdx.x; i < n4; i += gridDim.x * 256) {
    const int flat = i * 4;
    const float* src = flat < 3 * HH * HH ? wih + flat : whh + (flat - 3 * HH * HH);
    const f32x4 v = *(const f32x4*)src;
    ushort4 hi, lo;
    hi.x = f2bf(v[0]); lo.x = f2bf(v[0] - bf2f(hi.x));
    hi.y = f2bf(v[1]); lo.y = f2bf(v[1] - bf2f(hi.y));
    hi.z = f2bf(v[2]); lo.z = f2bf(v[2] - bf2f(hi.z));
    hi.w = f2bf(v[3]); lo.w = f2bf(v[3] - bf2f(hi.w));
    ((ushort4*)ghi)[i] = hi;
    ((ushort4*)glo)[i] = lo;
  }
}

// ---------------- GRU fused: 64 blocks x 12 waves (6 gates x 2 K-halves) ----------------
// Block owns 16 h-cols (B rows = 16 DISTINCT cols, no duplication). In-block epilogue.
__global__ __launch_bounds__(768, 1) void k_gruF(
    const unsigned short* __restrict__ xhi, const unsigned short* __restrict__ xlo,
    const unsigned short* __restrict__ hhi_s, const unsigned short* __restrict__ hlo_s,
    const unsigned short* __restrict__ ghi, const unsigned short* __restrict__ glo,
    const float* __restrict__ bih, const float* __restrict__ bhh,
    const float* __restrict__ hsrc, float* __restrict__ hdst,
    unsigned short* __restrict__ hhi_d, unsigned short* __restrict__ hlo_d) {
  __shared__ float g[12][64][17];                  // 52 KB, padded
  const int blk = blockIdx.x, tid = threadIdx.x;
  const int lane = tid & 63, wv = tid >> 6;        // 12 waves
  const int g6 = wv % 6, kh = wv / 6;
  const int cl = lane & 15, kk = (lane >> 4) * 8;
  const int j = blk * 16 + cl;
  const int kbeg = kh * 512;
  {
    const unsigned short* Ahi = g6 < 3 ? xhi : hhi_s;
    const unsigned short* Alo = g6 < 3 ? xlo : hlo_s;
    const unsigned short* bh = ghi + (size_t)(g6 * HH + j) * HH + kbeg;
    const unsigned short* bl = glo + (size_t)(g6 * HH + j) * HH + kbeg;
    const unsigned short* ah = Ahi + kbeg;
    const unsigned short* al = Alo + kbeg;
    f32x4 acc[4];
    acc[0] = acc[1] = acc[2] = acc[3] = (f32x4){0.f, 0.f, 0.f, 0.f};
    #pragma unroll 4
    for (int k0 = 0; k0 < 512; k0 += 32) {
      const bf16x8 whi = *(const bf16x8*)(bh + k0 + kk);
      const bf16x8 wlo = *(const bf16x8*)(bl + k0 + kk);
      #pragma unroll
      for (int rt = 0; rt < 4; ++rt) {
        const size_t aoff = (size_t)(rt * 16 + cl) * HH + k0 + kk;
        const bf16x8 a_h = *(const bf16x8*)(ah + aoff);
        const bf16x8 a_l = *(const bf16x8*)(al + aoff);
        acc[rt] = __builtin_amdgcn_mfma_f32_16x16x32_bf16(a_h, whi, acc[rt], 0, 0, 0);
        acc[rt] = __builtin_amdgcn_mfma_f32_16x16x32_bf16(a_l, whi, acc[rt], 0, 0, 0);
        acc[rt] = __builtin_amdgcn_mfma_f32_16x16x32_bf16(a_h, wlo, acc[rt], 0, 0, 0);
      }
    }
    #pragma unroll
    for (int rt = 0; rt < 4; ++rt)
      #pragma unroll
      for (int rg = 0; rg < 4; ++rg)
        g[wv][rt * 16 + (lane >> 4) * 4 + rg][cl] = acc[rt][rg];
  }
  __syncthreads();
  for (int e = tid; e < BB * 16; e += 768) {       // in-block epilogue
    const int b = e >> 4, c = e & 15;
    const int jj = blk * 16 + c;
    const size_t base = (size_t)b * HH + jj;
    const float gir = g[0][b][c] + g[6][b][c] + bih[jj];
    const float giz = g[1][b][c] + g[7][b][c] + bih[HH + jj];
    const float gin = g[2][b][c] + g[8][b][c] + bih[2 * HH + jj];
    const float ghr = g[3][b][c] + g[9][b][c] + bhh[jj];
    const float ghz = g[4][b][c] + g[10][b][c] + bhh[HH + jj];
    const float ghn = g[5][b][c] + g[11][b][c] + bhh[2 * HH + jj];
    const float r_ = 1.f / (1.f + __expf(-(gir + ghr)));
    const float z_ = 1.f / (1.f + __expf(-(giz + ghz)));
    const float n_ = tanhf(gin + r_ * ghn);
    const float hnew = (1.f - z_) * n_ + z_ * hsrc[base];
    hdst[base] = hnew;
    const unsigned short h16 = f2bf(hnew);
    hhi_d[base] = h16;
    hlo_d[base] = f2bf(hnew - bf2f(h16));
  }
}

// ---------------- logits: staged GEMM (round-6 proven) ----------------
__global__ __launch_bounds__(512, 1) void k_logits_lds(
    const unsigned short* __restrict__ hb,   // bf16 h [64][1024]
    const unsigned short* __restrict__ wbf,  // bf16 w_out [VV][1024]
    const float* __restrict__ bout, float* __restrict__ lbuf) {
  __shared__ __attribute__((aligned(16))) unsigned char sA[2][64 * BKL * 2];    // 2x16 KB
  __shared__ __attribute__((aligned(16))) unsigned char sB[2][128 * BKL * 2];   // 2x32 KB
  const int tid = threadIdx.x, blk = blockIdx.x;
  const int lane = tid & 63, wv = tid >> 6;
  const int cl = lane & 15, kk = (lane >> 4) * 8;

  auto STAGE = [&](int buf, int k0) {
    #pragma unroll
    for (int it = 0; it < 2; ++it) {
      const int c = it * 512 + tid;
      const int r = c >> 4;
      const int kb = (c & 15) * 16;
      const int kbs = kb ^ ((r & 7) << 4);           // inverse swizzle on source
      gld16(hb + (size_t)r * HH + k0 + (kbs >> 1),
            &sA[buf][it * 8192 + wv * 1024]);
    }
    #pragma unroll
    for (int it = 0; it < 4; ++it) {
      const int c = it * 512 + tid;
      const int col = c >> 4;
      const int kb = (c & 15) * 16;
      const int kbs = kb ^ ((col & 7) << 4);
      gld16(wbf + (size_t)(blk * 128 + col) * HH + k0 + (kbs >> 1),
            &sB[buf][it * 8192 + wv * 1024]);
    }
  };

  f32x4 acc[4];
  acc[0] = acc[1] = acc[2] = acc[3] = (f32x4){0.f, 0.f, 0.f, 0.f};

  STAGE(0, 0);
  for (int t = 0; t < HH / BKL; ++t) {               // 8 K-tiles
    const int cur = t & 1;
    if (t < HH / BKL - 1) {
      STAGE(cur ^ 1, (t + 1) * BKL);
      asm volatile("s_waitcnt vmcnt(6)" ::: "memory");
    } else {
      asm volatile("s_waitcnt vmcnt(0)" ::: "memory");
    }
    __builtin_amdgcn_s_barrier();
    __builtin_amdgcn_sched_barrier(0);
    #pragma unroll
    for (int ks = 0; ks < BKL; ks += 32) {
      const int bc = wv * 16 + cl;
      const bf16x8 bfr = *(const bf16x8*)&sB[cur][bc * (BKL * 2) + (((ks + kk) * 2) ^ ((bc & 7) << 4))];
      #pragma unroll
      for (int rt = 0; rt < 4; ++rt) {
        const int ar = rt * 16 + cl;
        const bf16x8 afr = *(const bf16x8*)&sA[cur][ar * (BKL * 2) + (((ks + kk) * 2) ^ ((ar & 7) << 4))];
        acc[rt] = __builtin_amdgcn_mfma_f32_16x16x32_bf16(afr, bfr, acc[rt], 0, 0, 0);
      }
    }
    __builtin_amdgcn_s_barrier();
    __builtin_amdgcn_sched_barrier(0);
  }

  const int col = blk * 128 + wv * 16 + cl;
  const float bo = bout[col];
  #pragma unroll
  for (int rt = 0; rt < 4; ++rt)
    #pragma unroll
    for (int rg = 0; rg < 4; ++rg) {
      const int row = rt * 16 + (lane >> 4) * 4 + rg;
      lbuf[(size_t)row * VV + col] = acc[rt][rg] + bo;
    }
}

// ---------------- quarter stats + per-quarter exact argmax recheck (round-6 proven) ----------------
__global__ __launch_bounds__(256) void k_sum(
    const float* __restrict__ lbuf, const float* __restrict__ wout,
    const float* __restrict__ bout, const float* __restrict__ hnew,
    float* __restrict__ mq, float* __restrict__ sq,
    float* __restrict__ qbestV, int* __restrict__ qbestI, int dorecheck) {
  __shared__ float srow[QS];
  __shared__ float red[4];
  __shared__ int icnt;
  __shared__ int scand[32];
  const int tid = threadIdx.x;
  const int b = blockIdx.x >> 2, q = blockIdx.x & 3;
  const int lane = tid & 63, wv = tid >> 6;
  const f32x4* src = (const f32x4*)(lbuf + (size_t)b * VV + q * QS);
  f32x4* s4 = (f32x4*)srow;

  float m = -3.0e38f;
  for (int i = tid; i < QS / 4; i += 256) {
    const f32x4 v = src[i];
    s4[i] = v;
    m = fmaxf(fmaxf(fmaxf(m, v[0]), v[1]), fmaxf(v[2], v[3]));
  }
  #pragma unroll
  for (int d = 1; d < 64; d <<= 1) m = fmaxf(m, __shfl_xor(m, d, 64));
  if (lane == 0) red[wv] = m;
  if (tid == 0) icnt = 0;
  __syncthreads();
  const float M = fmaxf(fmaxf(red[0], red[1]), fmaxf(red[2], red[3]));

  float s = 0.f;
  for (int i = tid; i < QS / 4; i += 256) {
    const f32x4 v = s4[i];
    s += __expf(v[0] - M) + __expf(v[1] - M) + __expf(v[2] - M) + __expf(v[3] - M);
  }
  #pragma unroll
  for (int d = 1; d < 64; d <<= 1) s += __shfl_xor(s, d, 64);
  __syncthreads();
  if (lane == 0) red[wv] = s;
  __syncthreads();
  if (tid == 0) {
    mq[b * 4 + q] = M;
    sq[b * 4 + q] = red[0] + red[1] + red[2] + red[3];
  }

  if (dorecheck) {
    const float thr = M - 0.05f;                     // quarter band superset of global band
    for (int i = tid; i < QS / 4; i += 256) {
      const f32x4 v = s4[i];
      #pragma unroll
      for (int u = 0; u < 4; ++u)
        if (v[u] >= thr) {
          const int c = atomicAdd(&icnt, 1);
          if (c < 32) scand[c] = q * QS + 4 * i + u;
        }
    }
    __syncthreads();
    if (wv == 0) {                                   // exact f32 recheck, wave 0
      const int nc = icnt < 32 ? icnt : 32;
      const float* hrow = hnew + (size_t)b * HH;
      f32x4 h4[4];
      #pragma unroll
      for (int u = 0; u < 4; ++u) h4[u] = *(const f32x4*)(hrow + lane * 16 + u * 4);
      float best = -3.0e38f; int bi = 0x7fffffff;
      for (int ci = 0; ci < nc; ++ci) {
        const int v = scand[ci];
        const float* wrow = wout + (size_t)v * HH + lane * 16;
        float ss = 0.f;
        #pragma unroll
        for (int u = 0; u < 4; ++u) {
          const f32x4 w4 = *(const f32x4*)(wrow + u * 4);
          ss += h4[u][0] * w4[0] + h4[u][1] * w4[1] + h4[u][2] * w4[2] + h4[u][3] * w4[3];
        }
        #pragma unroll
        for (int d = 1; d < 64; d <<= 1) ss += __shfl_xor(ss, d, 64);
        ss += bout[v];
        if (ss > best || (ss == best && v < bi)) { best = ss; bi = v; }
      }
      if (lane == 0) { qbestV[b * 4 + q] = best; qbestI[b * 4 + q] = bi; }
    }
  }
}

// ---------------- combine + out write + next-x (round-6 proven) ----------------
__global__ __launch_bounds__(256) void k_out(
    const float* __restrict__ lbuf, const float* __restrict__ mq,
    const float* __restrict__ sq, const float* __restrict__ qbestV,
    const int* __restrict__ qbestI, const float* __restrict__ emb,
    const float* __restrict__ hnew, float* __restrict__ out,
    unsigned short* __restrict__ xhi, unsigned short* __restrict__ xlo, int t) {
  __shared__ int stok;
  const int tid = threadIdx.x;
  const int b = blockIdx.x >> 2, q = blockIdx.x & 3;

  const float m0 = mq[b * 4 + 0], m1 = mq[b * 4 + 1];
  const float m2 = mq[b * 4 + 2], m3 = mq[b * 4 + 3];
  const float Mg = fmaxf(fmaxf(m0, m1), fmaxf(m2, m3));
  const float Sg = sq[b * 4 + 0] * __expf(m0 - Mg) + sq[b * 4 + 1] * __expf(m1 - Mg) +
                   sq[b * 4 + 2] * __expf(m2 - Mg) + sq[b * 4 + 3] * __expf(m3 - Mg);
  const float LZ = Mg + logf(Sg);

  const f32x4* src = (const f32x4*)(lbuf + (size_t)b * VV + q * QS);
  f32x4* dst = (f32x4*)(out + ((size_t)b * TT + t) * VV + q * QS);
  for (int i = tid; i < QS / 4; i += 256)
    dst[i] = src[i] - LZ;

  if (q == 0 && t < TT - 1) {
    if (tid == 0) {
      float bv = qbestV[b * 4 + 0]; int bi = qbestI[b * 4 + 0];
      #pragma unroll
      for (int qq = 1; qq < 4; ++qq) {
        const float v = qbestV[b * 4 + qq]; const int i2 = qbestI[b * 4 + qq];
        if (v > bv || (v == bv && i2 < bi)) { bv = v; bi = i2; }
      }
      stok = bi;
    }
    __syncthreads();
    const int tok = stok;
    for (int j = tid; j < HH; j += 256) {
      float e = emb[(size_t)tok * HH + j];
      e = e > 0.f ? e : 0.f;
      const unsigned short e16 = f2bf(e);
      xhi[(size_t)b * HH + j] = e16;
      xlo[(size_t)b * HH + j] = f2bf(e - bf2f(e16));
    }
  }
  if (q == 0 && t == TT - 1) {
    for (int j = tid; j < HH; j += 256)
      out[(size_t)BB * TT * VV + (size_t)b * HH + j] = hnew[(size_t)b * HH + j];
  }
}

// ================= fallback path (ws too small for caches) — round-6 proven =================
__global__ __launch_bounds__(64) void k_gru_fb(
    const unsigned short* __restrict__ xhi, const unsigned short* __restrict__ xlo,
    const unsigned short* __restrict__ hhi_s, const unsigned short* __restrict__ hlo_s,
    const float* __restrict__ wih, const float* __restrict__ whh,
    float* __restrict__ gbuf) {
  const int blk = blockIdx.x, lane = threadIdx.x;
  const int kh = blk & 1;
  const int r2 = blk >> 1;
  const int g6 = r2 % 6, jt = r2 / 6;
  const unsigned short* Ahi = g6 < 3 ? xhi : hhi_s;
  const unsigned short* Alo = g6 < 3 ? xlo : hlo_s;
  const int cl = lane & 15, kk = (lane >> 4) * 8;
  const int j = jt * 16 + cl;
  const int kbeg = kh * 512;
  f32x4 acc[4];
  acc[0] = acc[1] = acc[2] = acc[3] = (f32x4){0.f, 0.f, 0.f, 0.f};
  const float* W = (g6 < 3 ? wih : whh) + (size_t)((g6 % 3) * HH + j) * HH + kbeg;
  for (int k0 = 0; k0 < 512; k0 += 32) {
    const f32x4 w0 = *(const f32x4*)(W + k0 + kk);
    const f32x4 w1 = *(const f32x4*)(W + k0 + kk + 4);
    union { unsigned short u[8]; bf16x8 b; } chi, clo;
    #pragma unroll
    for (int u2 = 0; u2 < 4; ++u2) {
      chi.u[u2] = f2bf(w0[u2]); clo.u[u2] = f2bf(w0[u2] - bf2f(chi.u[u2]));
      chi.u[4 + u2] = f2bf(w1[u2]); clo.u[4 + u2] = f2bf(w1[u2] - bf2f(chi.u[4 + u2]));
    }
    #pragma unroll
    for (int rt = 0; rt < 4; ++rt) {
      const size_t aoff = (size_t)(rt * 16 + cl) * HH + kbeg + k0 + kk;
      const bf16x8 a_h = *(const bf16x8*)(Ahi + aoff);
      const bf16x8 a_l = *(const bf16x8*)(Alo + aoff);
      acc[rt] = __builtin_amdgcn_mfma_f32_16x16x32_bf16(a_h, chi.b, acc[rt], 0, 0, 0);
      acc[rt] = __builtin_amdgcn_mfma_f32_16x16x32_bf16(a_l, chi.b, acc[rt], 0, 0, 0);
      acc[rt] = __builtin_amdgcn_mfma_f32_16x16x32_bf16(a_h, clo.b, acc[rt], 0, 0, 0);
    }
  }
  #pragma unroll
  for (int rt = 0; rt < 4; ++rt)
    #pragma unroll
    for (int rg = 0; rg < 4; ++rg) {
      const int row = rt * 16 + (lane >> 4) * 4 + rg;
      gbuf[(size_t)((kh * 6 + g6) * BB + row) * HH + jt * 16 + cl] = acc[rt][rg];
    }
}

__global__ __launch_bounds__(256) void k_gep(
    const float* __restrict__ gbuf, const float* __restrict__ bih,
    const float* __restrict__ bhh, const float* __restrict__ hsrc,
    float* __restrict__ hdst, unsigned short* __restrict__ hhi_d,
    unsigned short* __restrict__ hlo_d) {
  const int e = blockIdx.x * 256 + threadIdx.x;
  const int b = e >> 10, j = e & (HH - 1);
  const size_t base = (size_t)b * HH + j;
  const float gir = gbuf[(size_t)(0 * BB + b) * HH + j] + gbuf[(size_t)((6 + 0) * BB + b) * HH + j] + bih[j];
  const float giz = gbuf[(size_t)(1 * BB + b) * HH + j] + gbuf[(size_t)((6 + 1) * BB + b) * HH + j] + bih[HH + j];
  const float gin = gbuf[(size_t)(2 * BB + b) * HH + j] + gbuf[(size_t)((6 + 2) * BB + b) * HH + j] + bih[2 * HH + j];
  const float ghr = gbuf[(size_t)(3 * BB + b) * HH + j] + gbuf[(size_t)((6 + 3) * BB + b) * HH + j] + bhh[j];
  const float ghz = gbuf[(size_t)(4 * BB + b) * HH + j] + gbuf[(size_t)((6 + 4) * BB + b) * HH + j] + bhh[HH + j];
  const float ghn = gbuf[(size_t)(5 * BB + b) * HH + j] + gbuf[(size_t)((6 + 5) * BB + b) * HH + j] + bhh[2 * HH + j];
  const float r_ = 1.f / (1.f + __expf(-(gir + ghr)));
  const float z_ = 1.f / (1.f + __expf(-(giz + ghz)));
  const float n_ = tanhf(gin + r_ * ghn);
  const float hnew = (1.f - z_) * n_ + z_ * hsrc[base];
  hdst[base] = hnew;
  const unsigned short h16 = f2bf(hnew);
  hhi_d[base] = h16;
  hlo_d[base] = f2bf(hnew - bf2f(h16));
}

__global__ __launch_bounds__(256) void k_logits_fb(
    const unsigned short* __restrict__ hb, const float* __restrict__ wout,
    const float* __restrict__ bout, float* __restrict__ lbuf) {
  const int tid = threadIdx.x, blk = blockIdx.x;
  const int lane = tid & 63, wv = tid >> 6;
  const int n0 = blk * 64 + wv * 16;
  const int cl = lane & 15, kk = (lane >> 4) * 8;
  f32x4 acc[4];
  acc[0] = acc[1] = acc[2] = acc[3] = (f32x4){0.f, 0.f, 0.f, 0.f};
  const float* wrow = wout + (size_t)(n0 + cl) * HH;
  for (int k0 = 0; k0 < HH; k0 += 32) {
    const f32x4 w0 = *(const f32x4*)(wrow + k0 + kk);
    const f32x4 w1 = *(const f32x4*)(wrow + k0 + kk + 4);
    union { unsigned short u[8]; bf16x8 b; } cv;
    #pragma unroll
    for (int u2 = 0; u2 < 4; ++u2) { cv.u[u2] = f2bf(w0[u2]); cv.u[4 + u2] = f2bf(w1[u2]); }
    #pragma unroll
    for (int rt = 0; rt < 4; ++rt) {
      const bf16x8 afr = *(const bf16x8*)(hb + (size_t)(rt * 16 + cl) * HH + k0 + kk);
      acc[rt] = __builtin_amdgcn_mfma_f32_16x16x32_bf16(afr, cv.b, acc[rt], 0, 0, 0);
    }
  }
  const int col = n0 + cl;
  const float bo = bout[col];
  #pragma unroll
  for (int rt = 0; rt < 4; ++rt)
    #pragma unroll
    for (int rg = 0; rg < 4; ++rg) {
      const int row = rt * 16 + (lane >> 4) * 4 + rg;
      lbuf[(size_t)row * VV + col] = acc[rt][rg] + bo;
    }
}

extern "C" void kernel_launch(void* const* d_in, const int* in_sizes, int n_in,
                              void* d_out, int out_size, void* d_ws, size_t ws_size,
                              hipStream_t stream) {
  const float* enc  = (const float*)d_in[1];
  const float* emb  = (const float*)d_in[2];
  const float* wih  = (const float*)d_in[3];
  const float* whh  = (const float*)d_in[4];
  const float* bih  = (const float*)d_in[5];
  const float* bhh  = (const float*)d_in[6];
  const float* wout = (const float*)d_in[7];
  const float* bout = (const float*)d_in[8];
  float* out = (float*)d_out;

  char* ws = (char*)d_ws;
  size_t off = 0;
  auto alloc = [&](size_t bytes) -> char* {
    char* p = ws + off;
    off += (bytes + 255) & ~(size_t)255;
    return p;
  };
  float* hrm = (float*)alloc((size_t)2 * BB * HH * 4);
  unsigned short* hhi = (unsigned short*)alloc((size_t)2 * BB * HH * 2);
  unsigned short* hlo = (unsigned short*)alloc((size_t)2 * BB * HH * 2);
  unsigned short* xhi = (unsigned short*)alloc((size_t)BB * HH * 2);
  unsigned short* xlo = (unsigned short*)alloc((size_t)BB * HH * 2);
  float* gbuf = (float*)alloc((size_t)12 * BB * HH * 4);
  float* lbuf = (float*)alloc((size_t)BB * VV * 4);
  float* mq = (float*)alloc((size_t)BB * 4 * 4);
  float* sq = (float*)alloc((size_t)BB * 4 * 4);
  float* qbestV = (float*)alloc((size_t)BB * 4 * 4);
  int* qbestI = (int*)alloc((size_t)BB * 4 * 4);
  unsigned short* wbf = (unsigned short*)alloc((size_t)VV * HH * 2);
  unsigned short* ghi = (unsigned short*)alloc((size_t)6 * HH * HH * 2);
  unsigned short* glo = (unsigned short*)alloc((size_t)6 * HH * HH * 2);
  const int cache_ok = (ws_size >= off) ? 1 : 0;

  hipLaunchKernelGGL(k_init, dim3(64), dim3(1024), 0, stream,
                     enc, emb, hrm, hhi, hlo, xhi, xlo);
  if (cache_ok) {
    hipLaunchKernelGGL(k_wconv, dim3(2048), dim3(256), 0, stream, wout, wbf);
    hipLaunchKernelGGL(k_wconv2, dim3(1024), dim3(256), 0, stream, wih, whh, ghi, glo);
  }

  for (int t = 0; t < TT; ++t) {
    const int p = t & 1;
    const float* hsrc = hrm + (size_t)p * BB * HH;
    float* hdst = hrm + (size_t)(p ^ 1) * BB * HH;
    const unsigned short* hhs = hhi + (size_t)p * BB * HH;
    const unsigned short* hls = hlo + (size_t)p * BB * HH;
    unsigned short* hhd = hhi + (size_t)(p ^ 1) * BB * HH;
    unsigned short* hld = hlo + (size_t)(p ^ 1) * BB * HH;

    if (cache_ok) {
      hipLaunchKernelGGL(k_gruF, dim3(64), dim3(768), 0, stream,
                         xhi, xlo, hhs, hls, ghi, glo, bih, bhh,
                         hsrc, hdst, hhd, hld);
      hipLaunchKernelGGL(k_logits_lds, dim3(250), dim3(512), 0, stream,
                         hhd, wbf, bout, lbuf);
    } else {
      hipLaunchKernelGGL(k_gru_fb, dim3(768), dim3(64), 0, stream,
                         xhi, xlo, hhs, hls, wih, whh, gbuf);
      hipLaunchKernelGGL(k_gep, dim3(256), dim3(256), 0, stream,
                         gbuf, bih, bhh, hsrc, hdst, hhd, hld);
      hipLaunchKernelGGL(k_logits_fb, dim3(500), dim3(256), 0, stream,
                         hhd, wout, bout, lbuf);
    }
    hipLaunchKernelGGL(k_sum, dim3(256), dim3(256), 0, stream,
                       lbuf, wout, bout, hdst, mq, sq, qbestV, qbestI,
                       (t < TT - 1) ? 1 : 0);
    hipLaunchKernelGGL(k_out, dim3(256), dim3(256), 0, stream,
                       lbuf, mq, sq, qbestV, qbestI, emb, hdst, out, xhi, xlo, t);
  }
}

// Round 11
// 1114.539 us; speedup vs baseline: 1.2515x; 1.2515x over previous
//
#include <hip/hip_runtime.h>
#include <math.h>

#define BB 64
#define HH 1024
#define VV 32000
#define TT 13
#define QS 8000            // VV/4 per quarter
#define BKL 128            // K-tile for staged logits GEMM

typedef float f32x4 __attribute__((ext_vector_type(4)));
typedef __bf16 bf16x8 __attribute__((ext_vector_type(8)));

__device__ __forceinline__ unsigned short f2bf(float f) {   // RNE
  unsigned u = __float_as_uint(f);
  u = (u + 0x7fffu + ((u >> 16) & 1u)) >> 16;
  return (unsigned short)u;
}
__device__ __forceinline__ float bf2f(unsigned short s) {
  return __uint_as_float(((unsigned)s) << 16);
}

// async global->LDS, 16B per lane; LDS dest = wave-uniform base + lane*16
__device__ __forceinline__ void gld16(const void* g, void* l) {
  __builtin_amdgcn_global_load_lds(
      (const __attribute__((address_space(1))) unsigned int*)g,
      (__attribute__((address_space(3))) unsigned int*)l, 16, 0, 0);
}

// ---------------- init: h0/x0 + splits ----------------
__global__ __launch_bounds__(1024) void k_init(
    const float* __restrict__ enc, const float* __restrict__ emb,
    float* __restrict__ hrm, unsigned short* __restrict__ hhi,
    unsigned short* __restrict__ hlo, unsigned short* __restrict__ xhi,
    unsigned short* __restrict__ xlo) {
  const int g = blockIdx.x * 1024 + threadIdx.x;
  const float h = enc[g];
  hrm[g] = h;
  const unsigned short h16 = f2bf(h);
  hhi[g] = h16;
  hlo[g] = f2bf(h - bf2f(h16));
  float e = emb[threadIdx.x];
  e = e > 0.f ? e : 0.f;
  const unsigned short e16 = f2bf(e);
  xhi[g] = e16;
  xlo[g] = f2bf(e - bf2f(e16));
}

// ---------------- one-time w_out -> bf16 ----------------
__global__ __launch_bounds__(256) void k_wconv(const float* __restrict__ w,
                                               unsigned short* __restrict__ o) {
  const int n4 = VV * HH / 4;
  for (int i = blockIdx.x * 256 + threadIdx.x; i < n4; i += gridDim.x * 256) {
    const f32x4 v = ((const f32x4*)w)[i];
    ushort4 u;
    u.x = f2bf(v[0]); u.y = f2bf(v[1]); u.z = f2bf(v[2]); u.w = f2bf(v[3]);
    ((ushort4*)o)[i] = u;
  }
}

// ---------------- one-time wih/whh -> bf16 hi/lo split ----------------
__global__ __launch_bounds__(256) void k_wconv2(
    const float* __restrict__ wih, const float* __restrict__ whh,
    unsigned short* __restrict__ ghi, unsigned short* __restrict__ glo) {
  const int n4 = 6 * HH * HH / 4;
  for (int i = blockIdx.x * 256 + threadIdx.x; i < n4; i += gridDim.x * 256) {
    const int flat = i * 4;
    const float* src = flat < 3 * HH * HH ? wih + flat : whh + (flat - 3 * HH * HH);
    const f32x4 v = *(const f32x4*)src;
    ushort4 hi, lo;
    hi.x = f2bf(v[0]); lo.x = f2bf(v[0] - bf2f(hi.x));
    hi.y = f2bf(v[1]); lo.y = f2bf(v[1] - bf2f(hi.y));
    hi.z = f2bf(v[2]); lo.z = f2bf(v[2] - bf2f(hi.z));
    hi.w = f2bf(v[3]); lo.w = f2bf(v[3] - bf2f(hi.w));
    ((ushort4*)ghi)[i] = hi;
    ((ushort4*)glo)[i] = lo;
  }
}

// ---------------- one-time relu(emb) -> bf16 hi/lo split (relu commutes with lookup) ----------------
__global__ __launch_bounds__(256) void k_wconv3(
    const float* __restrict__ emb, unsigned short* __restrict__ ehi,
    unsigned short* __restrict__ elo) {
  const int n4 = VV * HH / 4;
  for (int i = blockIdx.x * 256 + threadIdx.x; i < n4; i += gridDim.x * 256) {
    f32x4 v = ((const f32x4*)emb)[i];
    #pragma unroll
    for (int u = 0; u < 4; ++u) v[u] = v[u] > 0.f ? v[u] : 0.f;
    ushort4 hi, lo;
    hi.x = f2bf(v[0]); lo.x = f2bf(v[0] - bf2f(hi.x));
    hi.y = f2bf(v[1]); lo.y = f2bf(v[1] - bf2f(hi.y));
    hi.z = f2bf(v[2]); lo.z = f2bf(v[2] - bf2f(hi.z));
    hi.w = f2bf(v[3]); lo.w = f2bf(v[3] - bf2f(hi.w));
    ((ushort4*)ehi)[i] = hi;
    ((ushort4*)elo)[i] = lo;
  }
}

// ---------------- GRU gates w/ in-kernel token resolve + emb gather ----------------
// 768 one-wave blocks (proven geometry): blk -> (kh, g6, jt).
// ih blocks (g6<3): preamble combines per-quarter exact bests -> tok_b, then A-rows
// gathered from ehi/elo[tok_b] (pre-relu'd, pre-split -> identical inner loop).
__global__ __launch_bounds__(64) void k_gruG(
    const unsigned short* __restrict__ ehi, const unsigned short* __restrict__ elo,
    const unsigned short* __restrict__ hhi_s, const unsigned short* __restrict__ hlo_s,
    const unsigned short* __restrict__ ghi, const unsigned short* __restrict__ glo,
    const float* __restrict__ qbestV, const int* __restrict__ qbestI,
    float* __restrict__ gbuf, int use_qbest) {
  __shared__ int stok[64];
  const int blk = blockIdx.x, lane = threadIdx.x;
  const int kh = blk & 1;
  const int r2 = blk >> 1;
  const int g6 = r2 % 6, jt = r2 / 6;
  const int cl = lane & 15, kk = (lane >> 4) * 8;
  const int j = jt * 16 + cl;
  const int kbeg = kh * 512;
  const bool ih = g6 < 3;

  if (ih) {                                        // tok_b for b = lane
    int tok = 0;
    if (use_qbest) {
      float bv = qbestV[lane * 4 + 0]; int bi = qbestI[lane * 4 + 0];
      #pragma unroll
      for (int qq = 1; qq < 4; ++qq) {
        const float v = qbestV[lane * 4 + qq]; const int i2 = qbestI[lane * 4 + qq];
        if (v > bv || (v == bv && i2 < bi)) { bv = v; bi = i2; }
      }
      tok = bi;
    }
    stok[lane] = tok;
  }
  __syncthreads();

  size_t abase[4];
  #pragma unroll
  for (int rt = 0; rt < 4; ++rt) {
    const int row = rt * 16 + cl;
    abase[rt] = (ih ? (size_t)stok[row] : (size_t)row) * HH + kbeg + kk;
  }
  const unsigned short* Ahi = ih ? ehi : hhi_s;
  const unsigned short* Alo = ih ? elo : hlo_s;
  const unsigned short* bh = ghi + (size_t)(g6 * HH + j) * HH + kbeg;
  const unsigned short* bl = glo + (size_t)(g6 * HH + j) * HH + kbeg;

  f32x4 acc[4];
  acc[0] = acc[1] = acc[2] = acc[3] = (f32x4){0.f, 0.f, 0.f, 0.f};
  #pragma unroll 4
  for (int k0 = 0; k0 < 512; k0 += 32) {
    const bf16x8 whi = *(const bf16x8*)(bh + k0 + kk);
    const bf16x8 wlo = *(const bf16x8*)(bl + k0 + kk);
    #pragma unroll
    for (int rt = 0; rt < 4; ++rt) {
      const bf16x8 a_h = *(const bf16x8*)(Ahi + abase[rt] + k0);
      const bf16x8 a_l = *(const bf16x8*)(Alo + abase[rt] + k0);
      acc[rt] = __builtin_amdgcn_mfma_f32_16x16x32_bf16(a_h, whi, acc[rt], 0, 0, 0);
      acc[rt] = __builtin_amdgcn_mfma_f32_16x16x32_bf16(a_l, whi, acc[rt], 0, 0, 0);
      acc[rt] = __builtin_amdgcn_mfma_f32_16x16x32_bf16(a_h, wlo, acc[rt], 0, 0, 0);
    }
  }
  #pragma unroll
  for (int rt = 0; rt < 4; ++rt)
    #pragma unroll
    for (int rg = 0; rg < 4; ++rg) {
      const int row = rt * 16 + (lane >> 4) * 4 + rg;
      gbuf[(size_t)((kh * 6 + g6) * BB + row) * HH + jt * 16 + cl] = acc[rt][rg];
    }
}

// ---------------- GRU epilogue + prev-step out-write (LZ from mq/sq in LDS) ----------------
__global__ __launch_bounds__(256) void k_gepO(
    const float* __restrict__ gbuf, const float* __restrict__ bih,
    const float* __restrict__ bhh, const float* __restrict__ hsrc,
    float* __restrict__ hdst, unsigned short* __restrict__ hhi_d,
    unsigned short* __restrict__ hlo_d,
    const float* __restrict__ lbufPrev, const float* __restrict__ mq,
    const float* __restrict__ sq, float* __restrict__ out, int t) {
  __shared__ float lz[BB];
  const int tid = threadIdx.x;
  const int gid = blockIdx.x * 256 + tid;
  if (t > 0 && tid < BB) {
    const int b = tid;
    const float m0 = mq[b * 4 + 0], m1 = mq[b * 4 + 1];
    const float m2 = mq[b * 4 + 2], m3 = mq[b * 4 + 3];
    const float Mg = fmaxf(fmaxf(m0, m1), fmaxf(m2, m3));
    const float Sg = sq[b * 4 + 0] * __expf(m0 - Mg) + sq[b * 4 + 1] * __expf(m1 - Mg) +
                     sq[b * 4 + 2] * __expf(m2 - Mg) + sq[b * 4 + 3] * __expf(m3 - Mg);
    lz[b] = Mg + logf(Sg);
  }
  __syncthreads();
  {
    const int b = gid >> 10, j = gid & (HH - 1);
    const size_t base = (size_t)b * HH + j;
    const float gir = gbuf[(size_t)(0 * BB + b) * HH + j] + gbuf[(size_t)((6 + 0) * BB + b) * HH + j] + bih[j];
    const float giz = gbuf[(size_t)(1 * BB + b) * HH + j] + gbuf[(size_t)((6 + 1) * BB + b) * HH + j] + bih[HH + j];
    const float gin = gbuf[(size_t)(2 * BB + b) * HH + j] + gbuf[(size_t)((6 + 2) * BB + b) * HH + j] + bih[2 * HH + j];
    const float ghr = gbuf[(size_t)(3 * BB + b) * HH + j] + gbuf[(size_t)((6 + 3) * BB + b) * HH + j] + bhh[j];
    const float ghz = gbuf[(size_t)(4 * BB + b) * HH + j] + gbuf[(size_t)((6 + 4) * BB + b) * HH + j] + bhh[HH + j];
    const float ghn = gbuf[(size_t)(5 * BB + b) * HH + j] + gbuf[(size_t)((6 + 5) * BB + b) * HH + j] + bhh[2 * HH + j];
    const float r_ = 1.f / (1.f + __expf(-(gir + ghr)));
    const float z_ = 1.f / (1.f + __expf(-(giz + ghz)));
    const float n_ = tanhf(gin + r_ * ghn);
    const float hnew = (1.f - z_) * n_ + z_ * hsrc[base];
    hdst[base] = hnew;
    const unsigned short h16 = f2bf(hnew);
    hhi_d[base] = h16;
    hlo_d[base] = f2bf(hnew - bf2f(h16));
  }
  if (t > 0) {
    const f32x4* src = (const f32x4*)lbufPrev;
    for (int i4 = gid; i4 < BB * VV / 4; i4 += 65536) {
      const int b = i4 / (VV / 4);
      const f32x4 v = src[i4];
      ((f32x4*)out)[(size_t)(b * TT + (t - 1)) * (VV / 4) + (i4 - b * (VV / 4))] = v - lz[b];
    }
  }
}

// ---------------- logits: staged GEMM (round-6 proven) ----------------
__global__ __launch_bounds__(512, 1) void k_logits_lds(
    const unsigned short* __restrict__ hb,
    const unsigned short* __restrict__ wbf,
    const float* __restrict__ bout, float* __restrict__ lbuf) {
  __shared__ __attribute__((aligned(16))) unsigned char sA[2][64 * BKL * 2];
  __shared__ __attribute__((aligned(16))) unsigned char sB[2][128 * BKL * 2];
  const int tid = threadIdx.x, blk = blockIdx.x;
  const int lane = tid & 63, wv = tid >> 6;
  const int cl = lane & 15, kk = (lane >> 4) * 8;

  auto STAGE = [&](int buf, int k0) {
    #pragma unroll
    for (int it = 0; it < 2; ++it) {
      const int c = it * 512 + tid;
      const int r = c >> 4;
      const int kb = (c & 15) * 16;
      const int kbs = kb ^ ((r & 7) << 4);
      gld16(hb + (size_t)r * HH + k0 + (kbs >> 1),
            &sA[buf][it * 8192 + wv * 1024]);
    }
    #pragma unroll
    for (int it = 0; it < 4; ++it) {
      const int c = it * 512 + tid;
      const int col = c >> 4;
      const int kb = (c & 15) * 16;
      const int kbs = kb ^ ((col & 7) << 4);
      gld16(wbf + (size_t)(blk * 128 + col) * HH + k0 + (kbs >> 1),
            &sB[buf][it * 8192 + wv * 1024]);
    }
  };

  f32x4 acc[4];
  acc[0] = acc[1] = acc[2] = acc[3] = (f32x4){0.f, 0.f, 0.f, 0.f};

  STAGE(0, 0);
  for (int t = 0; t < HH / BKL; ++t) {
    const int cur = t & 1;
    if (t < HH / BKL - 1) {
      STAGE(cur ^ 1, (t + 1) * BKL);
      asm volatile("s_waitcnt vmcnt(6)" ::: "memory");
    } else {
      asm volatile("s_waitcnt vmcnt(0)" ::: "memory");
    }
    __builtin_amdgcn_s_barrier();
    __builtin_amdgcn_sched_barrier(0);
    #pragma unroll
    for (int ks = 0; ks < BKL; ks += 32) {
      const int bc = wv * 16 + cl;
      const bf16x8 bfr = *(const bf16x8*)&sB[cur][bc * (BKL * 2) + (((ks + kk) * 2) ^ ((bc & 7) << 4))];
      #pragma unroll
      for (int rt = 0; rt < 4; ++rt) {
        const int ar = rt * 16 + cl;
        const bf16x8 afr = *(const bf16x8*)&sA[cur][ar * (BKL * 2) + (((ks + kk) * 2) ^ ((ar & 7) << 4))];
        acc[rt] = __builtin_amdgcn_mfma_f32_16x16x32_bf16(afr, bfr, acc[rt], 0, 0, 0);
      }
    }
    __builtin_amdgcn_s_barrier();
    __builtin_amdgcn_sched_barrier(0);
  }

  const int col = blk * 128 + wv * 16 + cl;
  const float bo = bout[col];
  #pragma unroll
  for (int rt = 0; rt < 4; ++rt)
    #pragma unroll
    for (int rg = 0; rg < 4; ++rg) {
      const int row = rt * 16 + (lane >> 4) * 4 + rg;
      lbuf[(size_t)row * VV + col] = acc[rt][rg] + bo;
    }
}

// ---------------- quarter stats + per-quarter exact argmax recheck (round-6 proven) ----------------
__global__ __launch_bounds__(256) void k_sum(
    const float* __restrict__ lbuf, const float* __restrict__ wout,
    const float* __restrict__ bout, const float* __restrict__ hnew,
    float* __restrict__ mq, float* __restrict__ sq,
    float* __restrict__ qbestV, int* __restrict__ qbestI, int dorecheck) {
  __shared__ float srow[QS];
  __shared__ float red[4];
  __shared__ int icnt;
  __shared__ int scand[32];
  const int tid = threadIdx.x;
  const int b = blockIdx.x >> 2, q = blockIdx.x & 3;
  const int lane = tid & 63, wv = tid >> 6;
  const f32x4* src = (const f32x4*)(lbuf + (size_t)b * VV + q * QS);
  f32x4* s4 = (f32x4*)srow;

  float m = -3.0e38f;
  for (int i = tid; i < QS / 4; i += 256) {
    const f32x4 v = src[i];
    s4[i] = v;
    m = fmaxf(fmaxf(fmaxf(m, v[0]), v[1]), fmaxf(v[2], v[3]));
  }
  #pragma unroll
  for (int d = 1; d < 64; d <<= 1) m = fmaxf(m, __shfl_xor(m, d, 64));
  if (lane == 0) red[wv] = m;
  if (tid == 0) icnt = 0;
  __syncthreads();
  const float M = fmaxf(fmaxf(red[0], red[1]), fmaxf(red[2], red[3]));

  float s = 0.f;
  for (int i = tid; i < QS / 4; i += 256) {
    const f32x4 v = s4[i];
    s += __expf(v[0] - M) + __expf(v[1] - M) + __expf(v[2] - M) + __expf(v[3] - M);
  }
  #pragma unroll
  for (int d = 1; d < 64; d <<= 1) s += __shfl_xor(s, d, 64);
  __syncthreads();
  if (lane == 0) red[wv] = s;
  __syncthreads();
  if (tid == 0) {
    mq[b * 4 + q] = M;
    sq[b * 4 + q] = red[0] + red[1] + red[2] + red[3];
  }

  if (dorecheck) {
    const float thr = M - 0.05f;
    for (int i = tid; i < QS / 4; i += 256) {
      const f32x4 v = s4[i];
      #pragma unroll
      for (int u = 0; u < 4; ++u)
        if (v[u] >= thr) {
          const int c = atomicAdd(&icnt, 1);
          if (c < 32) scand[c] = q * QS + 4 * i + u;
        }
    }
    __syncthreads();
    if (wv == 0) {
      const int nc = icnt < 32 ? icnt : 32;
      const float* hrow = hnew + (size_t)b * HH;
      f32x4 h4[4];
      #pragma unroll
      for (int u = 0; u < 4; ++u) h4[u] = *(const f32x4*)(hrow + lane * 16 + u * 4);
      float best = -3.0e38f; int bi = 0x7fffffff;
      for (int ci = 0; ci < nc; ++ci) {
        const int v = scand[ci];
        const float* wrow = wout + (size_t)v * HH + lane * 16;
        float ss = 0.f;
        #pragma unroll
        for (int u = 0; u < 4; ++u) {
          const f32x4 w4 = *(const f32x4*)(wrow + u * 4);
          ss += h4[u][0] * w4[0] + h4[u][1] * w4[1] + h4[u][2] * w4[2] + h4[u][3] * w4[3];
        }
        #pragma unroll
        for (int d = 1; d < 64; d <<= 1) ss += __shfl_xor(ss, d, 64);
        ss += bout[v];
        if (ss > best || (ss == best && v < bi)) { best = ss; bi = v; }
      }
      if (lane == 0) { qbestV[b * 4 + q] = best; qbestI[b * 4 + q] = bi; }
    }
  }
}

// ---------------- finalize: out for t=12 + h_final ----------------
__global__ __launch_bounds__(256) void k_fin(
    const float* __restrict__ lbufLast, const float* __restrict__ mq,
    const float* __restrict__ sq, const float* __restrict__ hfin,
    float* __restrict__ out) {
  __shared__ float lz[BB];
  const int tid = threadIdx.x;
  const int gid = blockIdx.x * 256 + tid;
  if (tid < BB) {
    const int b = tid;
    const float m0 = mq[b * 4 + 0], m1 = mq[b * 4 + 1];
    const float m2 = mq[b * 4 + 2], m3 = mq[b * 4 + 3];
    const float Mg = fmaxf(fmaxf(m0, m1), fmaxf(m2, m3));
    const float Sg = sq[b * 4 + 0] * __expf(m0 - Mg) + sq[b * 4 + 1] * __expf(m1 - Mg) +
                     sq[b * 4 + 2] * __expf(m2 - Mg) + sq[b * 4 + 3] * __expf(m3 - Mg);
    lz[b] = Mg + logf(Sg);
  }
  __syncthreads();
  const f32x4* src = (const f32x4*)lbufLast;
  for (int i4 = gid; i4 < BB * VV / 4; i4 += 65536) {
    const int b = i4 / (VV / 4);
    const f32x4 v = src[i4];
    ((f32x4*)out)[(size_t)(b * TT + (TT - 1)) * (VV / 4) + (i4 - b * (VV / 4))] = v - lz[b];
  }
  out[(size_t)BB * TT * VV + gid] = hfin[gid];
}

// ================= fallback path (ws too small for caches) — round-6 proven =================
__global__ __launch_bounds__(64) void k_gru_fb(
    const unsigned short* __restrict__ xhi, const unsigned short* __restrict__ xlo,
    const unsigned short* __restrict__ hhi_s, const unsigned short* __restrict__ hlo_s,
    const float* __restrict__ wih, const float* __restrict__ whh,
    float* __restrict__ gbuf) {
  const int blk = blockIdx.x, lane = threadIdx.x;
  const int kh = blk & 1;
  const int r2 = blk >> 1;
  const int g6 = r2 % 6, jt = r2 / 6;
  const unsigned short* Ahi = g6 < 3 ? xhi : hhi_s;
  const unsigned short* Alo = g6 < 3 ? xlo : hlo_s;
  const int cl = lane & 15, kk = (lane >> 4) * 8;
  const int j = jt * 16 + cl;
  const int kbeg = kh * 512;
  f32x4 acc[4];
  acc[0] = acc[1] = acc[2] = acc[3] = (f32x4){0.f, 0.f, 0.f, 0.f};
  const float* W = (g6 < 3 ? wih : whh) + (size_t)((g6 % 3) * HH + j) * HH + kbeg;
  for (int k0 = 0; k0 < 512; k0 += 32) {
    const f32x4 w0 = *(const f32x4*)(W + k0 + kk);
    const f32x4 w1 = *(const f32x4*)(W + k0 + kk + 4);
    union { unsigned short u[8]; bf16x8 b; } chi, clo;
    #pragma unroll
    for (int u2 = 0; u2 < 4; ++u2) {
      chi.u[u2] = f2bf(w0[u2]); clo.u[u2] = f2bf(w0[u2] - bf2f(chi.u[u2]));
      chi.u[4 + u2] = f2bf(w1[u2]); clo.u[4 + u2] = f2bf(w1[u2] - bf2f(chi.u[4 + u2]));
    }
    #pragma unroll
    for (int rt = 0; rt < 4; ++rt) {
      const size_t aoff = (size_t)(rt * 16 + cl) * HH + kbeg + k0 + kk;
      const bf16x8 a_h = *(const bf16x8*)(Ahi + aoff);
      const bf16x8 a_l = *(const bf16x8*)(Alo + aoff);
      acc[rt] = __builtin_amdgcn_mfma_f32_16x16x32_bf16(a_h, chi.b, acc[rt], 0, 0, 0);
      acc[rt] = __builtin_amdgcn_mfma_f32_16x16x32_bf16(a_l, chi.b, acc[rt], 0, 0, 0);
      acc[rt] = __builtin_amdgcn_mfma_f32_16x16x32_bf16(a_h, clo.b, acc[rt], 0, 0, 0);
    }
  }
  #pragma unroll
  for (int rt = 0; rt < 4; ++rt)
    #pragma unroll
    for (int rg = 0; rg < 4; ++rg) {
      const int row = rt * 16 + (lane >> 4) * 4 + rg;
      gbuf[(size_t)((kh * 6 + g6) * BB + row) * HH + jt * 16 + cl] = acc[rt][rg];
    }
}

__global__ __launch_bounds__(256) void k_gep_fb(
    const float* __restrict__ gbuf, const float* __restrict__ bih,
    const float* __restrict__ bhh, const float* __restrict__ hsrc,
    float* __restrict__ hdst, unsigned short* __restrict__ hhi_d,
    unsigned short* __restrict__ hlo_d) {
  const int e = blockIdx.x * 256 + threadIdx.x;
  const int b = e >> 10, j = e & (HH - 1);
  const size_t base = (size_t)b * HH + j;
  const float gir = gbuf[(size_t)(0 * BB + b) * HH + j] + gbuf[(size_t)((6 + 0) * BB + b) * HH + j] + bih[j];
  const float giz = gbuf[(size_t)(1 * BB + b) * HH + j] + gbuf[(size_t)((6 + 1) * BB + b) * HH + j] + bih[HH + j];
  const float gin = gbuf[(size_t)(2 * BB + b) * HH + j] + gbuf[(size_t)((6 + 2) * BB + b) * HH + j] + bih[2 * HH + j];
  const float ghr = gbuf[(size_t)(3 * BB + b) * HH + j] + gbuf[(size_t)((6 + 3) * BB + b) * HH + j] + bhh[j];
  const float ghz = gbuf[(size_t)(4 * BB + b) * HH + j] + gbuf[(size_t)((6 + 4) * BB + b) * HH + j] + bhh[HH + j];
  const float ghn = gbuf[(size_t)(5 * BB + b) * HH + j] + gbuf[(size_t)((6 + 5) * BB + b) * HH + j] + bhh[2 * HH + j];
  const float r_ = 1.f / (1.f + __expf(-(gir + ghr)));
  const float z_ = 1.f / (1.f + __expf(-(giz + ghz)));
  const float n_ = tanhf(gin + r_ * ghn);
  const float hnew = (1.f - z_) * n_ + z_ * hsrc[base];
  hdst[base] = hnew;
  const unsigned short h16 = f2bf(hnew);
  hhi_d[base] = h16;
  hlo_d[base] = f2bf(hnew - bf2f(h16));
}

__global__ __launch_bounds__(256) void k_logits_fb(
    const unsigned short* __restrict__ hb, const float* __restrict__ wout,
    const float* __restrict__ bout, float* __restrict__ lbuf) {
  const int tid = threadIdx.x, blk = blockIdx.x;
  const int lane = tid & 63, wv = tid >> 6;
  const int n0 = blk * 64 + wv * 16;
  const int cl = lane & 15, kk = (lane >> 4) * 8;
  f32x4 acc[4];
  acc[0] = acc[1] = acc[2] = acc[3] = (f32x4){0.f, 0.f, 0.f, 0.f};
  const float* wrow = wout + (size_t)(n0 + cl) * HH;
  for (int k0 = 0; k0 < HH; k0 += 32) {
    const f32x4 w0 = *(const f32x4*)(wrow + k0 + kk);
    const f32x4 w1 = *(const f32x4*)(wrow + k0 + kk + 4);
    union { unsigned short u[8]; bf16x8 b; } cv;
    #pragma unroll
    for (int u2 = 0; u2 < 4; ++u2) { cv.u[u2] = f2bf(w0[u2]); cv.u[4 + u2] = f2bf(w1[u2]); }
    #pragma unroll
    for (int rt = 0; rt < 4; ++rt) {
      const bf16x8 afr = *(const bf16x8*)(hb + (size_t)(rt * 16 + cl) * HH + k0 + kk);
      acc[rt] = __builtin_amdgcn_mfma_f32_16x16x32_bf16(afr, cv.b, acc[rt], 0, 0, 0);
    }
  }
  const int col = n0 + cl;
  const float bo = bout[col];
  #pragma unroll
  for (int rt = 0; rt < 4; ++rt)
    #pragma unroll
    for (int rg = 0; rg < 4; ++rg) {
      const int row = rt * 16 + (lane >> 4) * 4 + rg;
      lbuf[(size_t)row * VV + col] = acc[rt][rg] + bo;
    }
}

__global__ __launch_bounds__(256) void k_out_fb(
    const float* __restrict__ lbuf, const float* __restrict__ mq,
    const float* __restrict__ sq, const float* __restrict__ qbestV,
    const int* __restrict__ qbestI, const float* __restrict__ emb,
    const float* __restrict__ hnew, float* __restrict__ out,
    unsigned short* __restrict__ xhi, unsigned short* __restrict__ xlo, int t) {
  __shared__ int stok;
  const int tid = threadIdx.x;
  const int b = blockIdx.x >> 2, q = blockIdx.x & 3;
  const float m0 = mq[b * 4 + 0], m1 = mq[b * 4 + 1];
  const float m2 = mq[b * 4 + 2], m3 = mq[b * 4 + 3];
  const float Mg = fmaxf(fmaxf(m0, m1), fmaxf(m2, m3));
  const float Sg = sq[b * 4 + 0] * __expf(m0 - Mg) + sq[b * 4 + 1] * __expf(m1 - Mg) +
                   sq[b * 4 + 2] * __expf(m2 - Mg) + sq[b * 4 + 3] * __expf(m3 - Mg);
  const float LZ = Mg + logf(Sg);
  const f32x4* src = (const f32x4*)(lbuf + (size_t)b * VV + q * QS);
  f32x4* dst = (f32x4*)(out + ((size_t)b * TT + t) * VV + q * QS);
  for (int i = tid; i < QS / 4; i += 256)
    dst[i] = src[i] - LZ;
  if (q == 0 && t < TT - 1) {
    if (tid == 0) {
      float bv = qbestV[b * 4 + 0]; int bi = qbestI[b * 4 + 0];
      #pragma unroll
      for (int qq = 1; qq < 4; ++qq) {
        const float v = qbestV[b * 4 + qq]; const int i2 = qbestI[b * 4 + qq];
        if (v > bv || (v == bv && i2 < bi)) { bv = v; bi = i2; }
      }
      stok = bi;
    }
    __syncthreads();
    const int tok = stok;
    for (int j = tid; j < HH; j += 256) {
      float e = emb[(size_t)tok * HH + j];
      e = e > 0.f ? e : 0.f;
      const unsigned short e16 = f2bf(e);
      xhi[(size_t)b * HH + j] = e16;
      xlo[(size_t)b * HH + j] = f2bf(e - bf2f(e16));
    }
  }
  if (q == 0 && t == TT - 1) {
    for (int j = tid; j < HH; j += 256)
      out[(size_t)BB * TT * VV + (size_t)b * HH + j] = hnew[(size_t)b * HH + j];
  }
}

extern "C" void kernel_launch(void* const* d_in, const int* in_sizes, int n_in,
                              void* d_out, int out_size, void* d_ws, size_t ws_size,
                              hipStream_t stream) {
  const float* enc  = (const float*)d_in[1];
  const float* emb  = (const float*)d_in[2];
  const float* wih  = (const float*)d_in[3];
  const float* whh  = (const float*)d_in[4];
  const float* bih  = (const float*)d_in[5];
  const float* bhh  = (const float*)d_in[6];
  const float* wout = (const float*)d_in[7];
  const float* bout = (const float*)d_in[8];
  float* out = (float*)d_out;

  char* ws = (char*)d_ws;
  size_t off = 0;
  auto alloc = [&](size_t bytes) -> char* {
    char* p = ws + off;
    off += (bytes + 255) & ~(size_t)255;
    return p;
  };
  float* hrm = (float*)alloc((size_t)2 * BB * HH * 4);
  unsigned short* hhi = (unsigned short*)alloc((size_t)2 * BB * HH * 2);
  unsigned short* hlo = (unsigned short*)alloc((size_t)2 * BB * HH * 2);
  unsigned short* xhi = (unsigned short*)alloc((size_t)BB * HH * 2);
  unsigned short* xlo = (unsigned short*)alloc((size_t)BB * HH * 2);
  float* gbuf = (float*)alloc((size_t)12 * BB * HH * 4);
  float* lbuf = (float*)alloc((size_t)2 * BB * VV * 4);   // double-buffered
  float* mq = (float*)alloc((size_t)BB * 4 * 4);
  float* sq = (float*)alloc((size_t)BB * 4 * 4);
  float* qbestV = (float*)alloc((size_t)BB * 4 * 4);
  int* qbestI = (int*)alloc((size_t)BB * 4 * 4);
  unsigned short* wbf = (unsigned short*)alloc((size_t)VV * HH * 2);
  unsigned short* ghi = (unsigned short*)alloc((size_t)6 * HH * HH * 2);
  unsigned short* glo = (unsigned short*)alloc((size_t)6 * HH * HH * 2);
  unsigned short* ehi = (unsigned short*)alloc((size_t)VV * HH * 2);
  unsigned short* elo = (unsigned short*)alloc((size_t)VV * HH * 2);
  const int cache_ok = (ws_size >= off) ? 1 : 0;

  hipLaunchKernelGGL(k_init, dim3(64), dim3(1024), 0, stream,
                     enc, emb, hrm, hhi, hlo, xhi, xlo);
  if (cache_ok) {
    hipLaunchKernelGGL(k_wconv, dim3(2048), dim3(256), 0, stream, wout, wbf);
    hipLaunchKernelGGL(k_wconv2, dim3(1024), dim3(256), 0, stream, wih, whh, ghi, glo);
    hipLaunchKernelGGL(k_wconv3, dim3(2048), dim3(256), 0, stream, emb, ehi, elo);
  }

  for (int t = 0; t < TT; ++t) {
    const int p = t & 1;
    const float* hsrc = hrm + (size_t)p * BB * HH;
    float* hdst = hrm + (size_t)(p ^ 1) * BB * HH;
    const unsigned short* hhs = hhi + (size_t)p * BB * HH;
    const unsigned short* hls = hlo + (size_t)p * BB * HH;
    unsigned short* hhd = hhi + (size_t)(p ^ 1) * BB * HH;
    unsigned short* hld = hlo + (size_t)(p ^ 1) * BB * HH;
    float* lb = lbuf + (size_t)(t & 1) * BB * VV;
    const float* lbPrev = lbuf + (size_t)((t & 1) ^ 1) * BB * VV;

    if (cache_ok) {
      hipLaunchKernelGGL(k_gruG, dim3(768), dim3(64), 0, stream,
                         ehi, elo, hhs, hls, ghi, glo, qbestV, qbestI,
                         gbuf, (t > 0) ? 1 : 0);
      hipLaunchKernelGGL(k_gepO, dim3(256), dim3(256), 0, stream,
                         gbuf, bih, bhh, hsrc, hdst, hhd, hld,
                         lbPrev, mq, sq, out, t);
      hipLaunchKernelGGL(k_logits_lds, dim3(250), dim3(512), 0, stream,
                         hhd, wbf, bout, lb);
      hipLaunchKernelGGL(k_sum, dim3(256), dim3(256), 0, stream,
                         lb, wout, bout, hdst, mq, sq, qbestV, qbestI,
                         (t < TT - 1) ? 1 : 0);
    } else {
      hipLaunchKernelGGL(k_gru_fb, dim3(768), dim3(64), 0, stream,
                         xhi, xlo, hhs, hls, wih, whh, gbuf);
      hipLaunchKernelGGL(k_gep_fb, dim3(256), dim3(256), 0, stream,
                         gbuf, bih, bhh, hsrc, hdst, hhd, hld);
      hipLaunchKernelGGL(k_logits_fb, dim3(500), dim3(256), 0, stream,
                         hhd, wout, bout, lb);
      hipLaunchKernelGGL(k_sum, dim3(256), dim3(256), 0, stream,
                         lb, wout, bout, hdst, mq, sq, qbestV, qbestI,
                         (t < TT - 1) ? 1 : 0);
      hipLaunchKernelGGL(k_out_fb, dim3(256), dim3(256), 0, stream,
                         lb, mq, sq, qbestV, qbestI, emb, hdst, out, xhi, xlo, t);
    }
  }

  if (cache_ok)
    hipLaunchKernelGGL(k_fin, dim3(256), dim3(256), 0, stream,
                       lbuf + (size_t)((TT - 1) & 1) * BB * VV, mq, sq,
                       hrm + (size_t)BB * HH, out);
}

// Round 12
// 1033.737 us; speedup vs baseline: 1.3493x; 1.0782x over previous
//
#include <hip/hip_runtime.h>
#include <math.h>

#define BB 64
#define HH 1024
#define VV 32000
#define TT 13
#define QS 8000            // VV/4 per quarter
#define BKL 128            // K-tile for staged logits GEMM

typedef float f32x4 __attribute__((ext_vector_type(4)));
typedef __bf16 bf16x8 __attribute__((ext_vector_type(8)));

__device__ __forceinline__ unsigned short f2bf(float f) {   // RNE
  unsigned u = __float_as_uint(f);
  u = (u + 0x7fffu + ((u >> 16) & 1u)) >> 16;
  return (unsigned short)u;
}
__device__ __forceinline__ float bf2f(unsigned short s) {
  return __uint_as_float(((unsigned)s) << 16);
}

// async global->LDS, 16B per lane
__device__ __forceinline__ void gld16(const void* g, void* l) {
  __builtin_amdgcn_global_load_lds(
      (const __attribute__((address_space(1))) unsigned int*)g,
      (__attribute__((address_space(3))) unsigned int*)l, 16, 0, 0);
}

// ---------------- init: h0/x0 + splits ----------------
__global__ __launch_bounds__(1024) void k_init(
    const float* __restrict__ enc, const float* __restrict__ emb,
    float* __restrict__ hrm, unsigned short* __restrict__ hhi,
    unsigned short* __restrict__ hlo, unsigned short* __restrict__ xhi,
    unsigned short* __restrict__ xlo) {
  const int g = blockIdx.x * 1024 + threadIdx.x;
  const float h = enc[g];
  hrm[g] = h;
  const unsigned short h16 = f2bf(h);
  hhi[g] = h16;
  hlo[g] = f2bf(h - bf2f(h16));
  float e = emb[threadIdx.x];
  e = e > 0.f ? e : 0.f;
  const unsigned short e16 = f2bf(e);
  xhi[g] = e16;
  xlo[g] = f2bf(e - bf2f(e16));
}

// ---------------- one-time (per call): w_out -> bf16; wih/whh -> bf16 hi/lo ----------------
__global__ __launch_bounds__(256) void k_wconvAll(
    const float* __restrict__ wout, const float* __restrict__ wih,
    const float* __restrict__ whh, unsigned short* __restrict__ wbf,
    unsigned short* __restrict__ ghi, unsigned short* __restrict__ glo) {
  const int n4w = VV * HH / 4;
  const int n4g = 6 * HH * HH / 4;
  for (int i = blockIdx.x * 256 + threadIdx.x; i < n4w + n4g; i += gridDim.x * 256) {
    if (i < n4w) {
      const f32x4 v = ((const f32x4*)wout)[i];
      ushort4 u;
      u.x = f2bf(v[0]); u.y = f2bf(v[1]); u.z = f2bf(v[2]); u.w = f2bf(v[3]);
      ((ushort4*)wbf)[i] = u;
    } else {
      const int k = i - n4w;
      const int flat = k * 4;
      const float* src = flat < 3 * HH * HH ? wih + flat : whh + (flat - 3 * HH * HH);
      const f32x4 v = *(const f32x4*)src;
      ushort4 hi, lo;
      hi.x = f2bf(v[0]); lo.x = f2bf(v[0] - bf2f(hi.x));
      hi.y = f2bf(v[1]); lo.y = f2bf(v[1] - bf2f(hi.y));
      hi.z = f2bf(v[2]); lo.z = f2bf(v[2] - bf2f(hi.z));
      hi.w = f2bf(v[3]); lo.w = f2bf(v[3] - bf2f(hi.w));
      ((ushort4*)ghi)[k] = hi;
      ((ushort4*)glo)[k] = lo;
    }
  }
}

// ---------------- GRU gates: 768 one-wave blocks; ih blocks resolve tok + gather emb ----------------
// blk -> (kh, g6, jt). ih (g6<3): A from f32 emb[tok] w/ inline relu+RNE split.
__global__ __launch_bounds__(64) void k_gru(
    const float* __restrict__ emb,
    const unsigned short* __restrict__ hhi_s, const unsigned short* __restrict__ hlo_s,
    const unsigned short* __restrict__ ghi, const unsigned short* __restrict__ glo,
    const float* __restrict__ qbestV, const int* __restrict__ qbestI,
    float* __restrict__ gbuf, int use_qbest) {
  __shared__ int stok[64];
  const int blk = blockIdx.x, lane = threadIdx.x;
  const int kh = blk & 1;
  const int r2 = blk >> 1;
  const int g6 = r2 % 6, jt = r2 / 6;
  const int cl = lane & 15, kk = (lane >> 4) * 8;
  const int j = jt * 16 + cl;
  const int kbeg = kh * 512;
  const bool ih = g6 < 3;

  if (ih) {
    int tok = 0;
    if (use_qbest) {
      float bv = qbestV[lane * 4 + 0]; int bi = qbestI[lane * 4 + 0];
      #pragma unroll
      for (int qq = 1; qq < 4; ++qq) {
        const float v = qbestV[lane * 4 + qq]; const int i2 = qbestI[lane * 4 + qq];
        if (v > bv || (v == bv && i2 < bi)) { bv = v; bi = i2; }
      }
      tok = bi;
    }
    stok[lane] = tok;
  }
  __syncthreads();

  const unsigned short* bh = ghi + (size_t)(g6 * HH + j) * HH + kbeg;
  const unsigned short* bl = glo + (size_t)(g6 * HH + j) * HH + kbeg;
  f32x4 acc[4];
  acc[0] = acc[1] = acc[2] = acc[3] = (f32x4){0.f, 0.f, 0.f, 0.f};

  if (ih) {
    const float* ap[4];
    #pragma unroll
    for (int rt = 0; rt < 4; ++rt)
      ap[rt] = emb + (size_t)stok[rt * 16 + cl] * HH + kbeg + kk;
    #pragma unroll 2
    for (int k0 = 0; k0 < 512; k0 += 32) {
      const bf16x8 whi = *(const bf16x8*)(bh + k0 + kk);
      const bf16x8 wlo = *(const bf16x8*)(bl + k0 + kk);
      #pragma unroll
      for (int rt = 0; rt < 4; ++rt) {
        const f32x4 a0 = *(const f32x4*)(ap[rt] + k0);
        const f32x4 a1 = *(const f32x4*)(ap[rt] + k0 + 4);
        union { unsigned short u[8]; bf16x8 b; } ah, al;
        #pragma unroll
        for (int u2 = 0; u2 < 4; ++u2) {
          const float v0 = a0[u2] > 0.f ? a0[u2] : 0.f;
          ah.u[u2] = f2bf(v0);
          al.u[u2] = f2bf(v0 - bf2f(ah.u[u2]));
          const float v1 = a1[u2] > 0.f ? a1[u2] : 0.f;
          ah.u[4 + u2] = f2bf(v1);
          al.u[4 + u2] = f2bf(v1 - bf2f(ah.u[4 + u2]));
        }
        acc[rt] = __builtin_amdgcn_mfma_f32_16x16x32_bf16(ah.b, whi, acc[rt], 0, 0, 0);
        acc[rt] = __builtin_amdgcn_mfma_f32_16x16x32_bf16(al.b, whi, acc[rt], 0, 0, 0);
        acc[rt] = __builtin_amdgcn_mfma_f32_16x16x32_bf16(ah.b, wlo, acc[rt], 0, 0, 0);
      }
    }
  } else {
    const unsigned short* ah = hhi_s + kbeg;
    const unsigned short* al = hlo_s + kbeg;
    #pragma unroll 4
    for (int k0 = 0; k0 < 512; k0 += 32) {
      const bf16x8 whi = *(const bf16x8*)(bh + k0 + kk);
      const bf16x8 wlo = *(const bf16x8*)(bl + k0 + kk);
      #pragma unroll
      for (int rt = 0; rt < 4; ++rt) {
        const size_t aoff = (size_t)(rt * 16 + cl) * HH + k0 + kk;
        const bf16x8 a_h = *(const bf16x8*)(ah + aoff);
        const bf16x8 a_l = *(const bf16x8*)(al + aoff);
        acc[rt] = __builtin_amdgcn_mfma_f32_16x16x32_bf16(a_h, whi, acc[rt], 0, 0, 0);
        acc[rt] = __builtin_amdgcn_mfma_f32_16x16x32_bf16(a_l, whi, acc[rt], 0, 0, 0);
        acc[rt] = __builtin_amdgcn_mfma_f32_16x16x32_bf16(a_h, wlo, acc[rt], 0, 0, 0);
      }
    }
  }
  #pragma unroll
  for (int rt = 0; rt < 4; ++rt)
    #pragma unroll
    for (int rg = 0; rg < 4; ++rg) {
      const int row = rt * 16 + (lane >> 4) * 4 + rg;
      gbuf[(size_t)((kh * 6 + g6) * BB + row) * HH + jt * 16 + cl] = acc[rt][rg];
    }
}

// ---------------- GRU epilogue (round-6 proven) ----------------
__global__ __launch_bounds__(256) void k_gep(
    const float* __restrict__ gbuf, const float* __restrict__ bih,
    const float* __restrict__ bhh, const float* __restrict__ hsrc,
    float* __restrict__ hdst, unsigned short* __restrict__ hhi_d,
    unsigned short* __restrict__ hlo_d) {
  const int e = blockIdx.x * 256 + threadIdx.x;
  const int b = e >> 10, j = e & (HH - 1);
  const size_t base = (size_t)b * HH + j;
  const float gir = gbuf[(size_t)(0 * BB + b) * HH + j] + gbuf[(size_t)((6 + 0) * BB + b) * HH + j] + bih[j];
  const float giz = gbuf[(size_t)(1 * BB + b) * HH + j] + gbuf[(size_t)((6 + 1) * BB + b) * HH + j] + bih[HH + j];
  const float gin = gbuf[(size_t)(2 * BB + b) * HH + j] + gbuf[(size_t)((6 + 2) * BB + b) * HH + j] + bih[2 * HH + j];
  const float ghr = gbuf[(size_t)(3 * BB + b) * HH + j] + gbuf[(size_t)((6 + 3) * BB + b) * HH + j] + bhh[j];
  const float ghz = gbuf[(size_t)(4 * BB + b) * HH + j] + gbuf[(size_t)((6 + 4) * BB + b) * HH + j] + bhh[HH + j];
  const float ghn = gbuf[(size_t)(5 * BB + b) * HH + j] + gbuf[(size_t)((6 + 5) * BB + b) * HH + j] + bhh[2 * HH + j];
  const float r_ = 1.f / (1.f + __expf(-(gir + ghr)));
  const float z_ = 1.f / (1.f + __expf(-(giz + ghz)));
  const float n_ = tanhf(gin + r_ * ghn);
  const float hnew = (1.f - z_) * n_ + z_ * hsrc[base];
  hdst[base] = hnew;
  const unsigned short h16 = f2bf(hnew);
  hhi_d[base] = h16;
  hlo_d[base] = f2bf(hnew - bf2f(h16));
}

// ---------------- logits: staged GEMM (round-6 proven) ----------------
__global__ __launch_bounds__(512, 1) void k_logits_lds(
    const unsigned short* __restrict__ hb,
    const unsigned short* __restrict__ wbf,
    const float* __restrict__ bout, float* __restrict__ lbuf) {
  __shared__ __attribute__((aligned(16))) unsigned char sA[2][64 * BKL * 2];
  __shared__ __attribute__((aligned(16))) unsigned char sB[2][128 * BKL * 2];
  const int tid = threadIdx.x, blk = blockIdx.x;
  const int lane = tid & 63, wv = tid >> 6;
  const int cl = lane & 15, kk = (lane >> 4) * 8;

  auto STAGE = [&](int buf, int k0) {
    #pragma unroll
    for (int it = 0; it < 2; ++it) {
      const int c = it * 512 + tid;
      const int r = c >> 4;
      const int kb = (c & 15) * 16;
      const int kbs = kb ^ ((r & 7) << 4);
      gld16(hb + (size_t)r * HH + k0 + (kbs >> 1),
            &sA[buf][it * 8192 + wv * 1024]);
    }
    #pragma unroll
    for (int it = 0; it < 4; ++it) {
      const int c = it * 512 + tid;
      const int col = c >> 4;
      const int kb = (c & 15) * 16;
      const int kbs = kb ^ ((col & 7) << 4);
      gld16(wbf + (size_t)(blk * 128 + col) * HH + k0 + (kbs >> 1),
            &sB[buf][it * 8192 + wv * 1024]);
    }
  };

  f32x4 acc[4];
  acc[0] = acc[1] = acc[2] = acc[3] = (f32x4){0.f, 0.f, 0.f, 0.f};

  STAGE(0, 0);
  for (int t = 0; t < HH / BKL; ++t) {
    const int cur = t & 1;
    if (t < HH / BKL - 1) {
      STAGE(cur ^ 1, (t + 1) * BKL);
      asm volatile("s_waitcnt vmcnt(6)" ::: "memory");
    } else {
      asm volatile("s_waitcnt vmcnt(0)" ::: "memory");
    }
    __builtin_amdgcn_s_barrier();
    __builtin_amdgcn_sched_barrier(0);
    #pragma unroll
    for (int ks = 0; ks < BKL; ks += 32) {
      const int bc = wv * 16 + cl;
      const bf16x8 bfr = *(const bf16x8*)&sB[cur][bc * (BKL * 2) + (((ks + kk) * 2) ^ ((bc & 7) << 4))];
      #pragma unroll
      for (int rt = 0; rt < 4; ++rt) {
        const int ar = rt * 16 + cl;
        const bf16x8 afr = *(const bf16x8*)&sA[cur][ar * (BKL * 2) + (((ks + kk) * 2) ^ ((ar & 7) << 4))];
        acc[rt] = __builtin_amdgcn_mfma_f32_16x16x32_bf16(afr, bfr, acc[rt], 0, 0, 0);
      }
    }
    __builtin_amdgcn_s_barrier();
    __builtin_amdgcn_sched_barrier(0);
  }

  const int col = blk * 128 + wv * 16 + cl;
  const float bo = bout[col];
  #pragma unroll
  for (int rt = 0; rt < 4; ++rt)
    #pragma unroll
    for (int rg = 0; rg < 4; ++rg) {
      const int row = rt * 16 + (lane >> 4) * 4 + rg;
      lbuf[(size_t)row * VV + col] = acc[rt][rg] + bo;
    }
}

// ---------------- quarter stats + per-quarter exact argmax recheck (round-6 proven) ----------------
__global__ __launch_bounds__(256) void k_sum(
    const float* __restrict__ lbuf, const float* __restrict__ wout,
    const float* __restrict__ bout, const float* __restrict__ hnew,
    float* __restrict__ mq, float* __restrict__ sq,
    float* __restrict__ qbestV, int* __restrict__ qbestI, int dorecheck) {
  __shared__ float srow[QS];
  __shared__ float red[4];
  __shared__ int icnt;
  __shared__ int scand[32];
  const int tid = threadIdx.x;
  const int b = blockIdx.x >> 2, q = blockIdx.x & 3;
  const int lane = tid & 63, wv = tid >> 6;
  const f32x4* src = (const f32x4*)(lbuf + (size_t)b * VV + q * QS);
  f32x4* s4 = (f32x4*)srow;

  float m = -3.0e38f;
  for (int i = tid; i < QS / 4; i += 256) {
    const f32x4 v = src[i];
    s4[i] = v;
    m = fmaxf(fmaxf(fmaxf(m, v[0]), v[1]), fmaxf(v[2], v[3]));
  }
  #pragma unroll
  for (int d = 1; d < 64; d <<= 1) m = fmaxf(m, __shfl_xor(m, d, 64));
  if (lane == 0) red[wv] = m;
  if (tid == 0) icnt = 0;
  __syncthreads();
  const float M = fmaxf(fmaxf(red[0], red[1]), fmaxf(red[2], red[3]));

  float s = 0.f;
  for (int i = tid; i < QS / 4; i += 256) {
    const f32x4 v = s4[i];
    s += __expf(v[0] - M) + __expf(v[1] - M) + __expf(v[2] - M) + __expf(v[3] - M);
  }
  #pragma unroll
  for (int d = 1; d < 64; d <<= 1) s += __shfl_xor(s, d, 64);
  __syncthreads();
  if (lane == 0) red[wv] = s;
  __syncthreads();
  if (tid == 0) {
    mq[b * 4 + q] = M;
    sq[b * 4 + q] = red[0] + red[1] + red[2] + red[3];
  }

  if (dorecheck) {
    const float thr = M - 0.05f;
    for (int i = tid; i < QS / 4; i += 256) {
      const f32x4 v = s4[i];
      #pragma unroll
      for (int u = 0; u < 4; ++u)
        if (v[u] >= thr) {
          const int c = atomicAdd(&icnt, 1);
          if (c < 32) scand[c] = q * QS + 4 * i + u;
        }
    }
    __syncthreads();
    if (wv == 0) {
      const int nc = icnt < 32 ? icnt : 32;
      const float* hrow = hnew + (size_t)b * HH;
      f32x4 h4[4];
      #pragma unroll
      for (int u = 0; u < 4; ++u) h4[u] = *(const f32x4*)(hrow + lane * 16 + u * 4);
      float best = -3.0e38f; int bi = 0x7fffffff;
      for (int ci = 0; ci < nc; ++ci) {
        const int v = scand[ci];
        const float* wrow = wout + (size_t)v * HH + lane * 16;
        float ss = 0.f;
        #pragma unroll
        for (int u = 0; u < 4; ++u) {
          const f32x4 w4 = *(const f32x4*)(wrow + u * 4);
          ss += h4[u][0] * w4[0] + h4[u][1] * w4[1] + h4[u][2] * w4[2] + h4[u][3] * w4[3];
        }
        #pragma unroll
        for (int d = 1; d < 64; d <<= 1) ss += __shfl_xor(ss, d, 64);
        ss += bout[v];
        if (ss > best || (ss == best && v < bi)) { best = ss; bi = v; }
      }
      if (lane == 0) { qbestV[b * 4 + q] = best; qbestI[b * 4 + q] = bi; }
    }
  }
}

// ---------------- batched out-write for ALL steps + h_final ----------------
// grid 840: blocks 0..831 -> (t = blk>>6, b = blk&63) plane; 832..839 -> h_final.
__global__ __launch_bounds__(256) void k_outAll(
    const float* __restrict__ lbuf,   // [TT][BB][VV]
    const float* __restrict__ mqT, const float* __restrict__ sqT,
    const float* __restrict__ hfin, float* __restrict__ out) {
  const int tid = threadIdx.x, blk = blockIdx.x;
  if (blk < TT * BB) {
    const int t = blk >> 6, b = blk & 63;
    const float m0 = mqT[t * BB * 4 + b * 4 + 0], m1 = mqT[t * BB * 4 + b * 4 + 1];
    const float m2 = mqT[t * BB * 4 + b * 4 + 2], m3 = mqT[t * BB * 4 + b * 4 + 3];
    const float Mg = fmaxf(fmaxf(m0, m1), fmaxf(m2, m3));
    const float Sg = sqT[t * BB * 4 + b * 4 + 0] * __expf(m0 - Mg) +
                     sqT[t * BB * 4 + b * 4 + 1] * __expf(m1 - Mg) +
                     sqT[t * BB * 4 + b * 4 + 2] * __expf(m2 - Mg) +
                     sqT[t * BB * 4 + b * 4 + 3] * __expf(m3 - Mg);
    const float LZ = Mg + logf(Sg);
    const f32x4* src = (const f32x4*)(lbuf + ((size_t)t * BB + b) * VV);
    f32x4* dst = (f32x4*)(out + ((size_t)b * TT + t) * VV);
    for (int i = tid; i < VV / 4; i += 256)
      dst[i] = src[i] - LZ;
  } else {
    const int local = (blk - TT * BB) * 256 + tid;
    for (int k = local; k < BB * HH; k += 8 * 256)
      out[(size_t)BB * TT * VV + k] = hfin[k];
  }
}

// ================= fallback path (ws too small) — round-6 proven =================
__global__ __launch_bounds__(64) void k_gru_fb(
    const unsigned short* __restrict__ xhi, const unsigned short* __restrict__ xlo,
    const unsigned short* __restrict__ hhi_s, const unsigned short* __restrict__ hlo_s,
    const float* __restrict__ wih, const float* __restrict__ whh,
    float* __restrict__ gbuf) {
  const int blk = blockIdx.x, lane = threadIdx.x;
  const int kh = blk & 1;
  const int r2 = blk >> 1;
  const int g6 = r2 % 6, jt = r2 / 6;
  const unsigned short* Ahi = g6 < 3 ? xhi : hhi_s;
  const unsigned short* Alo = g6 < 3 ? xlo : hlo_s;
  const int cl = lane & 15, kk = (lane >> 4) * 8;
  const int j = jt * 16 + cl;
  const int kbeg = kh * 512;
  f32x4 acc[4];
  acc[0] = acc[1] = acc[2] = acc[3] = (f32x4){0.f, 0.f, 0.f, 0.f};
  const float* W = (g6 < 3 ? wih : whh) + (size_t)((g6 % 3) * HH + j) * HH + kbeg;
  for (int k0 = 0; k0 < 512; k0 += 32) {
    const f32x4 w0 = *(const f32x4*)(W + k0 + kk);
    const f32x4 w1 = *(const f32x4*)(W + k0 + kk + 4);
    union { unsigned short u[8]; bf16x8 b; } chi, clo;
    #pragma unroll
    for (int u2 = 0; u2 < 4; ++u2) {
      chi.u[u2] = f2bf(w0[u2]); clo.u[u2] = f2bf(w0[u2] - bf2f(chi.u[u2]));
      chi.u[4 + u2] = f2bf(w1[u2]); clo.u[4 + u2] = f2bf(w1[u2] - bf2f(chi.u[4 + u2]));
    }
    #pragma unroll
    for (int rt = 0; rt < 4; ++rt) {
      const size_t aoff = (size_t)(rt * 16 + cl) * HH + kbeg + k0 + kk;
      const bf16x8 a_h = *(const bf16x8*)(Ahi + aoff);
      const bf16x8 a_l = *(const bf16x8*)(Alo + aoff);
      acc[rt] = __builtin_amdgcn_mfma_f32_16x16x32_bf16(a_h, chi.b, acc[rt], 0, 0, 0);
      acc[rt] = __builtin_amdgcn_mfma_f32_16x16x32_bf16(a_l, chi.b, acc[rt], 0, 0, 0);
      acc[rt] = __builtin_amdgcn_mfma_f32_16x16x32_bf16(a_h, clo.b, acc[rt], 0, 0, 0);
    }
  }
  #pragma unroll
  for (int rt = 0; rt < 4; ++rt)
    #pragma unroll
    for (int rg = 0; rg < 4; ++rg) {
      const int row = rt * 16 + (lane >> 4) * 4 + rg;
      gbuf[(size_t)((kh * 6 + g6) * BB + row) * HH + jt * 16 + cl] = acc[rt][rg];
    }
}

__global__ __launch_bounds__(256) void k_logits_fb(
    const unsigned short* __restrict__ hb, const float* __restrict__ wout,
    const float* __restrict__ bout, float* __restrict__ lbuf) {
  const int tid = threadIdx.x, blk = blockIdx.x;
  const int lane = tid & 63, wv = tid >> 6;
  const int n0 = blk * 64 + wv * 16;
  const int cl = lane & 15, kk = (lane >> 4) * 8;
  f32x4 acc[4];
  acc[0] = acc[1] = acc[2] = acc[3] = (f32x4){0.f, 0.f, 0.f, 0.f};
  const float* wrow = wout + (size_t)(n0 + cl) * HH;
  for (int k0 = 0; k0 < HH; k0 += 32) {
    const f32x4 w0 = *(const f32x4*)(wrow + k0 + kk);
    const f32x4 w1 = *(const f32x4*)(wrow + k0 + kk + 4);
    union { unsigned short u[8]; bf16x8 b; } cv;
    #pragma unroll
    for (int u2 = 0; u2 < 4; ++u2) { cv.u[u2] = f2bf(w0[u2]); cv.u[4 + u2] = f2bf(w1[u2]); }
    #pragma unroll
    for (int rt = 0; rt < 4; ++rt) {
      const bf16x8 afr = *(const bf16x8*)(hb + (size_t)(rt * 16 + cl) * HH + k0 + kk);
      acc[rt] = __builtin_amdgcn_mfma_f32_16x16x32_bf16(afr, cv.b, acc[rt], 0, 0, 0);
    }
  }
  const int col = n0 + cl;
  const float bo = bout[col];
  #pragma unroll
  for (int rt = 0; rt < 4; ++rt)
    #pragma unroll
    for (int rg = 0; rg < 4; ++rg) {
      const int row = rt * 16 + (lane >> 4) * 4 + rg;
      lbuf[(size_t)row * VV + col] = acc[rt][rg] + bo;
    }
}

__global__ __launch_bounds__(256) void k_out_fb(
    const float* __restrict__ lbuf, const float* __restrict__ mq,
    const float* __restrict__ sq, const float* __restrict__ qbestV,
    const int* __restrict__ qbestI, const float* __restrict__ emb,
    const float* __restrict__ hnew, float* __restrict__ out,
    unsigned short* __restrict__ xhi, unsigned short* __restrict__ xlo, int t) {
  __shared__ int stok;
  const int tid = threadIdx.x;
  const int b = blockIdx.x >> 2, q = blockIdx.x & 3;
  const float m0 = mq[b * 4 + 0], m1 = mq[b * 4 + 1];
  const float m2 = mq[b * 4 + 2], m3 = mq[b * 4 + 3];
  const float Mg = fmaxf(fmaxf(m0, m1), fmaxf(m2, m3));
  const float Sg = sq[b * 4 + 0] * __expf(m0 - Mg) + sq[b * 4 + 1] * __expf(m1 - Mg) +
                   sq[b * 4 + 2] * __expf(m2 - Mg) + sq[b * 4 + 3] * __expf(m3 - Mg);
  const float LZ = Mg + logf(Sg);
  const f32x4* src = (const f32x4*)(lbuf + (size_t)b * VV + q * QS);
  f32x4* dst = (f32x4*)(out + ((size_t)b * TT + t) * VV + q * QS);
  for (int i = tid; i < QS / 4; i += 256)
    dst[i] = src[i] - LZ;
  if (q == 0 && t < TT - 1) {
    if (tid == 0) {
      float bv = qbestV[b * 4 + 0]; int bi = qbestI[b * 4 + 0];
      #pragma unroll
      for (int qq = 1; qq < 4; ++qq) {
        const float v = qbestV[b * 4 + qq]; const int i2 = qbestI[b * 4 + qq];
        if (v > bv || (v == bv && i2 < bi)) { bv = v; bi = i2; }
      }
      stok = bi;
    }
    __syncthreads();
    const int tok = stok;
    for (int j = tid; j < HH; j += 256) {
      float e = emb[(size_t)tok * HH + j];
      e = e > 0.f ? e : 0.f;
      const unsigned short e16 = f2bf(e);
      xhi[(size_t)b * HH + j] = e16;
      xlo[(size_t)b * HH + j] = f2bf(e - bf2f(e16));
    }
  }
  if (q == 0 && t == TT - 1) {
    for (int j = tid; j < HH; j += 256)
      out[(size_t)BB * TT * VV + (size_t)b * HH + j] = hnew[(size_t)b * HH + j];
  }
}

__global__ __launch_bounds__(256) void k_gep_fb(
    const float* __restrict__ gbuf, const float* __restrict__ bih,
    const float* __restrict__ bhh, const float* __restrict__ hsrc,
    float* __restrict__ hdst, unsigned short* __restrict__ hhi_d,
    unsigned short* __restrict__ hlo_d) {
  const int e = blockIdx.x * 256 + threadIdx.x;
  const int b = e >> 10, j = e & (HH - 1);
  const size_t base = (size_t)b * HH + j;
  const float gir = gbuf[(size_t)(0 * BB + b) * HH + j] + gbuf[(size_t)((6 + 0) * BB + b) * HH + j] + bih[j];
  const float giz = gbuf[(size_t)(1 * BB + b) * HH + j] + gbuf[(size_t)((6 + 1) * BB + b) * HH + j] + bih[HH + j];
  const float gin = gbuf[(size_t)(2 * BB + b) * HH + j] + gbuf[(size_t)((6 + 2) * BB + b) * HH + j] + bih[2 * HH + j];
  const float ghr = gbuf[(size_t)(3 * BB + b) * HH + j] + gbuf[(size_t)((6 + 3) * BB + b) * HH + j] + bhh[j];
  const float ghz = gbuf[(size_t)(4 * BB + b) * HH + j] + gbuf[(size_t)((6 + 4) * BB + b) * HH + j] + bhh[HH + j];
  const float ghn = gbuf[(size_t)(5 * BB + b) * HH + j] + gbuf[(size_t)((6 + 5) * BB + b) * HH + j] + bhh[2 * HH + j];
  const float r_ = 1.f / (1.f + __expf(-(gir + ghr)));
  const float z_ = 1.f / (1.f + __expf(-(giz + ghz)));
  const float n_ = tanhf(gin + r_ * ghn);
  const float hnew = (1.f - z_) * n_ + z_ * hsrc[base];
  hdst[base] = hnew;
  const unsigned short h16 = f2bf(hnew);
  hhi_d[base] = h16;
  hlo_d[base] = f2bf(hnew - bf2f(h16));
}

extern "C" void kernel_launch(void* const* d_in, const int* in_sizes, int n_in,
                              void* d_out, int out_size, void* d_ws, size_t ws_size,
                              hipStream_t stream) {
  const float* enc  = (const float*)d_in[1];
  const float* emb  = (const float*)d_in[2];
  const float* wih  = (const float*)d_in[3];
  const float* whh  = (const float*)d_in[4];
  const float* bih  = (const float*)d_in[5];
  const float* bhh  = (const float*)d_in[6];
  const float* wout = (const float*)d_in[7];
  const float* bout = (const float*)d_in[8];
  float* out = (float*)d_out;

  char* ws = (char*)d_ws;
  size_t off = 0;
  auto alloc = [&](size_t bytes) -> char* {
    char* p = ws + off;
    off += (bytes + 255) & ~(size_t)255;
    return p;
  };
  float* hrm = (float*)alloc((size_t)2 * BB * HH * 4);
  unsigned short* hhi = (unsigned short*)alloc((size_t)2 * BB * HH * 2);
  unsigned short* hlo = (unsigned short*)alloc((size_t)2 * BB * HH * 2);
  unsigned short* xhi = (unsigned short*)alloc((size_t)BB * HH * 2);
  unsigned short* xlo = (unsigned short*)alloc((size_t)BB * HH * 2);
  float* gbuf = (float*)alloc((size_t)12 * BB * HH * 4);
  float* mqT = (float*)alloc((size_t)TT * BB * 4 * 4);
  float* sqT = (float*)alloc((size_t)TT * BB * 4 * 4);
  float* qbestV = (float*)alloc((size_t)BB * 4 * 4);
  int* qbestI = (int*)alloc((size_t)BB * 4 * 4);
  unsigned short* wbf = (unsigned short*)alloc((size_t)VV * HH * 2);
  unsigned short* ghi = (unsigned short*)alloc((size_t)6 * HH * HH * 2);
  unsigned short* glo = (unsigned short*)alloc((size_t)6 * HH * HH * 2);
  float* lbuf = (float*)alloc((size_t)TT * BB * VV * 4);    // 13 planes
  const int cache_ok = (ws_size >= off) ? 1 : 0;

  hipLaunchKernelGGL(k_init, dim3(64), dim3(1024), 0, stream,
                     enc, emb, hrm, hhi, hlo, xhi, xlo);

  if (cache_ok) {
    hipLaunchKernelGGL(k_wconvAll, dim3(2560), dim3(256), 0, stream,
                       wout, wih, whh, wbf, ghi, glo);

    for (int t = 0; t < TT; ++t) {
      const int p = t & 1;
      const float* hsrc = hrm + (size_t)p * BB * HH;
      float* hdst = hrm + (size_t)(p ^ 1) * BB * HH;
      const unsigned short* hhs = hhi + (size_t)p * BB * HH;
      const unsigned short* hls = hlo + (size_t)p * BB * HH;
      unsigned short* hhd = hhi + (size_t)(p ^ 1) * BB * HH;
      unsigned short* hld = hlo + (size_t)(p ^ 1) * BB * HH;
      float* lb = lbuf + (size_t)t * BB * VV;

      hipLaunchKernelGGL(k_gru, dim3(768), dim3(64), 0, stream,
                         emb, hhs, hls, ghi, glo, qbestV, qbestI,
                         gbuf, (t > 0) ? 1 : 0);
      hipLaunchKernelGGL(k_gep, dim3(256), dim3(256), 0, stream,
                         gbuf, bih, bhh, hsrc, hdst, hhd, hld);
      hipLaunchKernelGGL(k_logits_lds, dim3(250), dim3(512), 0, stream,
                         hhd, wbf, bout, lb);
      hipLaunchKernelGGL(k_sum, dim3(256), dim3(256), 0, stream,
                         lb, wout, bout, hdst,
                         mqT + (size_t)t * BB * 4, sqT + (size_t)t * BB * 4,
                         qbestV, qbestI, (t < TT - 1) ? 1 : 0);
    }
    hipLaunchKernelGGL(k_outAll, dim3(TT * BB + 8), dim3(256), 0, stream,
                       lbuf, mqT, sqT, hrm + (size_t)BB * HH, out);
  } else {
    // fallback: round-6 structure, single lbuf plane reused
    float* lb0 = lbuf;
    for (int t = 0; t < TT; ++t) {
      const int p = t & 1;
      const float* hsrc = hrm + (size_t)p * BB * HH;
      float* hdst = hrm + (size_t)(p ^ 1) * BB * HH;
      const unsigned short* hhs = hhi + (size_t)p * BB * HH;
      const unsigned short* hls = hlo + (size_t)p * BB * HH;
      unsigned short* hhd = hhi + (size_t)(p ^ 1) * BB * HH;
      unsigned short* hld = hlo + (size_t)(p ^ 1) * BB * HH;
      hipLaunchKernelGGL(k_gru_fb, dim3(768), dim3(64), 0, stream,
                         xhi, xlo, hhs, hls, wih, whh, gbuf);
      hipLaunchKernelGGL(k_gep_fb, dim3(256), dim3(256), 0, stream,
                         gbuf, bih, bhh, hsrc, hdst, hhd, hld);
      hipLaunchKernelGGL(k_logits_fb, dim3(500), dim3(256), 0, stream,
                         hhd, wout, bout, lb0);
      hipLaunchKernelGGL(k_sum, dim3(256), dim3(256), 0, stream,
                         lb0, wout, bout, hdst, mqT, sqT, qbestV, qbestI,
                         (t < TT - 1) ? 1 : 0);
      hipLaunchKernelGGL(k_out_fb, dim3(256), dim3(256), 0, stream,
                         lb0, mqT, sqT, qbestV, qbestI, emb, hdst, out, xhi, xlo, t);
    }
  }
}

// Round 13
// 1021.259 us; speedup vs baseline: 1.3658x; 1.0122x over previous
//
#include <hip/hip_runtime.h>
#include <math.h>

#define BB 64
#define HH 1024
#define VV 32000
#define TT 13
#define QS 8000            // VV/4 per quarter
#define BKL 128            // K-tile for staged logits GEMM

typedef float f32x4 __attribute__((ext_vector_type(4)));
typedef __bf16 bf16x8 __attribute__((ext_vector_type(8)));

__device__ __forceinline__ unsigned short f2bf(float f) {   // RNE
  unsigned u = __float_as_uint(f);
  u = (u + 0x7fffu + ((u >> 16) & 1u)) >> 16;
  return (unsigned short)u;
}
__device__ __forceinline__ float bf2f(unsigned short s) {
  return __uint_as_float(((unsigned)s) << 16);
}

// async global->LDS, 16B per lane
__device__ __forceinline__ void gld16(const void* g, void* l) {
  __builtin_amdgcn_global_load_lds(
      (const __attribute__((address_space(1))) unsigned int*)g,
      (__attribute__((address_space(3))) unsigned int*)l, 16, 0, 0);
}

// ---------------- init: h0/x0 + splits ----------------
__global__ __launch_bounds__(1024) void k_init(
    const float* __restrict__ enc, const float* __restrict__ emb,
    float* __restrict__ hrm, unsigned short* __restrict__ hhi,
    unsigned short* __restrict__ hlo, unsigned short* __restrict__ xhi,
    unsigned short* __restrict__ xlo) {
  const int g = blockIdx.x * 1024 + threadIdx.x;
  const float h = enc[g];
  hrm[g] = h;
  const unsigned short h16 = f2bf(h);
  hhi[g] = h16;
  hlo[g] = f2bf(h - bf2f(h16));
  float e = emb[threadIdx.x];
  e = e > 0.f ? e : 0.f;
  const unsigned short e16 = f2bf(e);
  xhi[g] = e16;
  xlo[g] = f2bf(e - bf2f(e16));
}

// ---------------- per-call: w_out -> bf16 (round-6 proven geometry) ----------------
__global__ __launch_bounds__(256) void k_wconv(const float* __restrict__ w,
                                               unsigned short* __restrict__ o) {
  const int n4 = VV * HH / 4;
  for (int i = blockIdx.x * 256 + threadIdx.x; i < n4; i += gridDim.x * 256) {
    const f32x4 v = ((const f32x4*)w)[i];
    ushort4 u;
    u.x = f2bf(v[0]); u.y = f2bf(v[1]); u.z = f2bf(v[2]); u.w = f2bf(v[3]);
    ((ushort4*)o)[i] = u;
  }
}

// ---------------- per-call: wih/whh -> bf16 hi/lo split (round-6 proven) ----------------
__global__ __launch_bounds__(256) void k_wconv2(
    const float* __restrict__ wih, const float* __restrict__ whh,
    unsigned short* __restrict__ ghi, unsigned short* __restrict__ glo) {
  const int n4 = 6 * HH * HH / 4;
  for (int i = blockIdx.x * 256 + threadIdx.x; i < n4; i += gridDim.x * 256) {
    const int flat = i * 4;
    const float* src = flat < 3 * HH * HH ? wih + flat : whh + (flat - 3 * HH * HH);
    const f32x4 v = *(const f32x4*)src;
    ushort4 hi, lo;
    hi.x = f2bf(v[0]); lo.x = f2bf(v[0] - bf2f(hi.x));
    hi.y = f2bf(v[1]); lo.y = f2bf(v[1] - bf2f(hi.y));
    hi.z = f2bf(v[2]); lo.z = f2bf(v[2] - bf2f(hi.z));
    hi.w = f2bf(v[3]); lo.w = f2bf(v[3] - bf2f(hi.w));
    ((ushort4*)ghi)[i] = hi;
    ((ushort4*)glo)[i] = lo;
  }
}

// ---------------- GRU gates (r12-proven): 768 one-wave blocks, token resolve + emb gather ----------------
__global__ __launch_bounds__(64) void k_gru(
    const float* __restrict__ emb,
    const unsigned short* __restrict__ hhi_s, const unsigned short* __restrict__ hlo_s,
    const unsigned short* __restrict__ ghi, const unsigned short* __restrict__ glo,
    const float* __restrict__ qbestV, const int* __restrict__ qbestI,
    float* __restrict__ gbuf, int use_qbest) {
  __shared__ int stok[64];
  const int blk = blockIdx.x, lane = threadIdx.x;
  const int kh = blk & 1;
  const int r2 = blk >> 1;
  const int g6 = r2 % 6, jt = r2 / 6;
  const int cl = lane & 15, kk = (lane >> 4) * 8;
  const int j = jt * 16 + cl;
  const int kbeg = kh * 512;
  const bool ih = g6 < 3;

  if (ih) {
    int tok = 0;
    if (use_qbest) {
      float bv = qbestV[lane * 4 + 0]; int bi = qbestI[lane * 4 + 0];
      #pragma unroll
      for (int qq = 1; qq < 4; ++qq) {
        const float v = qbestV[lane * 4 + qq]; const int i2 = qbestI[lane * 4 + qq];
        if (v > bv || (v == bv && i2 < bi)) { bv = v; bi = i2; }
      }
      tok = bi;
    }
    stok[lane] = tok;
  }
  __syncthreads();

  const unsigned short* bh = ghi + (size_t)(g6 * HH + j) * HH + kbeg;
  const unsigned short* bl = glo + (size_t)(g6 * HH + j) * HH + kbeg;
  f32x4 acc[4];
  acc[0] = acc[1] = acc[2] = acc[3] = (f32x4){0.f, 0.f, 0.f, 0.f};

  if (ih) {
    const float* ap[4];
    #pragma unroll
    for (int rt = 0; rt < 4; ++rt)
      ap[rt] = emb + (size_t)stok[rt * 16 + cl] * HH + kbeg + kk;
    #pragma unroll 2
    for (int k0 = 0; k0 < 512; k0 += 32) {
      const bf16x8 whi = *(const bf16x8*)(bh + k0 + kk);
      const bf16x8 wlo = *(const bf16x8*)(bl + k0 + kk);
      #pragma unroll
      for (int rt = 0; rt < 4; ++rt) {
        const f32x4 a0 = *(const f32x4*)(ap[rt] + k0);
        const f32x4 a1 = *(const f32x4*)(ap[rt] + k0 + 4);
        union { unsigned short u[8]; bf16x8 b; } ah, al;
        #pragma unroll
        for (int u2 = 0; u2 < 4; ++u2) {
          const float v0 = a0[u2] > 0.f ? a0[u2] : 0.f;
          ah.u[u2] = f2bf(v0);
          al.u[u2] = f2bf(v0 - bf2f(ah.u[u2]));
          const float v1 = a1[u2] > 0.f ? a1[u2] : 0.f;
          ah.u[4 + u2] = f2bf(v1);
          al.u[4 + u2] = f2bf(v1 - bf2f(ah.u[4 + u2]));
        }
        acc[rt] = __builtin_amdgcn_mfma_f32_16x16x32_bf16(ah.b, whi, acc[rt], 0, 0, 0);
        acc[rt] = __builtin_amdgcn_mfma_f32_16x16x32_bf16(al.b, whi, acc[rt], 0, 0, 0);
        acc[rt] = __builtin_amdgcn_mfma_f32_16x16x32_bf16(ah.b, wlo, acc[rt], 0, 0, 0);
      }
    }
  } else {
    const unsigned short* ah = hhi_s + kbeg;
    const unsigned short* al = hlo_s + kbeg;
    #pragma unroll 4
    for (int k0 = 0; k0 < 512; k0 += 32) {
      const bf16x8 whi = *(const bf16x8*)(bh + k0 + kk);
      const bf16x8 wlo = *(const bf16x8*)(bl + k0 + kk);
      #pragma unroll
      for (int rt = 0; rt < 4; ++rt) {
        const size_t aoff = (size_t)(rt * 16 + cl) * HH + k0 + kk;
        const bf16x8 a_h = *(const bf16x8*)(ah + aoff);
        const bf16x8 a_l = *(const bf16x8*)(al + aoff);
        acc[rt] = __builtin_amdgcn_mfma_f32_16x16x32_bf16(a_h, whi, acc[rt], 0, 0, 0);
        acc[rt] = __builtin_amdgcn_mfma_f32_16x16x32_bf16(a_l, whi, acc[rt], 0, 0, 0);
        acc[rt] = __builtin_amdgcn_mfma_f32_16x16x32_bf16(a_h, wlo, acc[rt], 0, 0, 0);
      }
    }
  }
  #pragma unroll
  for (int rt = 0; rt < 4; ++rt)
    #pragma unroll
    for (int rg = 0; rg < 4; ++rg) {
      const int row = rt * 16 + (lane >> 4) * 4 + rg;
      gbuf[(size_t)((kh * 6 + g6) * BB + row) * HH + jt * 16 + cl] = acc[rt][rg];
    }
}

// ---------------- GRU epilogue + prev-step out-write (r9-proven fusion) ----------------
__global__ __launch_bounds__(256) void k_gepO(
    const float* __restrict__ gbuf, const float* __restrict__ bih,
    const float* __restrict__ bhh, const float* __restrict__ hsrc,
    float* __restrict__ hdst, unsigned short* __restrict__ hhi_d,
    unsigned short* __restrict__ hlo_d,
    const float* __restrict__ lbufPrev, const float* __restrict__ mq,
    const float* __restrict__ sq, float* __restrict__ out, int t) {
  __shared__ float lz[BB];
  const int tid = threadIdx.x;
  const int gid = blockIdx.x * 256 + tid;
  if (t > 0 && tid < BB) {
    const int b = tid;
    const float m0 = mq[b * 4 + 0], m1 = mq[b * 4 + 1];
    const float m2 = mq[b * 4 + 2], m3 = mq[b * 4 + 3];
    const float Mg = fmaxf(fmaxf(m0, m1), fmaxf(m2, m3));
    const float Sg = sq[b * 4 + 0] * __expf(m0 - Mg) + sq[b * 4 + 1] * __expf(m1 - Mg) +
                     sq[b * 4 + 2] * __expf(m2 - Mg) + sq[b * 4 + 3] * __expf(m3 - Mg);
    lz[b] = Mg + logf(Sg);
  }
  __syncthreads();
  {
    const int b = gid >> 10, j = gid & (HH - 1);
    const size_t base = (size_t)b * HH + j;
    const float gir = gbuf[(size_t)(0 * BB + b) * HH + j] + gbuf[(size_t)((6 + 0) * BB + b) * HH + j] + bih[j];
    const float giz = gbuf[(size_t)(1 * BB + b) * HH + j] + gbuf[(size_t)((6 + 1) * BB + b) * HH + j] + bih[HH + j];
    const float gin = gbuf[(size_t)(2 * BB + b) * HH + j] + gbuf[(size_t)((6 + 2) * BB + b) * HH + j] + bih[2 * HH + j];
    const float ghr = gbuf[(size_t)(3 * BB + b) * HH + j] + gbuf[(size_t)((6 + 3) * BB + b) * HH + j] + bhh[j];
    const float ghz = gbuf[(size_t)(4 * BB + b) * HH + j] + gbuf[(size_t)((6 + 4) * BB + b) * HH + j] + bhh[HH + j];
    const float ghn = gbuf[(size_t)(5 * BB + b) * HH + j] + gbuf[(size_t)((6 + 5) * BB + b) * HH + j] + bhh[2 * HH + j];
    const float r_ = 1.f / (1.f + __expf(-(gir + ghr)));
    const float z_ = 1.f / (1.f + __expf(-(giz + ghz)));
    const float n_ = tanhf(gin + r_ * ghn);
    const float hnew = (1.f - z_) * n_ + z_ * hsrc[base];
    hdst[base] = hnew;
    const unsigned short h16 = f2bf(hnew);
    hhi_d[base] = h16;
    hlo_d[base] = f2bf(hnew - bf2f(h16));
  }
  if (t > 0) {
    const f32x4* src = (const f32x4*)lbufPrev;
    for (int i4 = gid; i4 < BB * VV / 4; i4 += 65536) {
      const int b = i4 / (VV / 4);
      const f32x4 v = src[i4];
      ((f32x4*)out)[(size_t)(b * TT + (t - 1)) * (VV / 4) + (i4 - b * (VV / 4))] = v - lz[b];
    }
  }
}

// ---------------- logits: staged GEMM (round-6 proven, untouched) ----------------
__global__ __launch_bounds__(512, 1) void k_logits_lds(
    const unsigned short* __restrict__ hb,
    const unsigned short* __restrict__ wbf,
    const float* __restrict__ bout, float* __restrict__ lbuf) {
  __shared__ __attribute__((aligned(16))) unsigned char sA[2][64 * BKL * 2];
  __shared__ __attribute__((aligned(16))) unsigned char sB[2][128 * BKL * 2];
  const int tid = threadIdx.x, blk = blockIdx.x;
  const int lane = tid & 63, wv = tid >> 6;
  const int cl = lane & 15, kk = (lane >> 4) * 8;

  auto STAGE = [&](int buf, int k0) {
    #pragma unroll
    for (int it = 0; it < 2; ++it) {
      const int c = it * 512 + tid;
      const int r = c >> 4;
      const int kb = (c & 15) * 16;
      const int kbs = kb ^ ((r & 7) << 4);
      gld16(hb + (size_t)r * HH + k0 + (kbs >> 1),
            &sA[buf][it * 8192 + wv * 1024]);
    }
    #pragma unroll
    for (int it = 0; it < 4; ++it) {
      const int c = it * 512 + tid;
      const int col = c >> 4;
      const int kb = (c & 15) * 16;
      const int kbs = kb ^ ((col & 7) << 4);
      gld16(wbf + (size_t)(blk * 128 + col) * HH + k0 + (kbs >> 1),
            &sB[buf][it * 8192 + wv * 1024]);
    }
  };

  f32x4 acc[4];
  acc[0] = acc[1] = acc[2] = acc[3] = (f32x4){0.f, 0.f, 0.f, 0.f};

  STAGE(0, 0);
  for (int t = 0; t < HH / BKL; ++t) {
    const int cur = t & 1;
    if (t < HH / BKL - 1) {
      STAGE(cur ^ 1, (t + 1) * BKL);
      asm volatile("s_waitcnt vmcnt(6)" ::: "memory");
    } else {
      asm volatile("s_waitcnt vmcnt(0)" ::: "memory");
    }
    __builtin_amdgcn_s_barrier();
    __builtin_amdgcn_sched_barrier(0);
    #pragma unroll
    for (int ks = 0; ks < BKL; ks += 32) {
      const int bc = wv * 16 + cl;
      const bf16x8 bfr = *(const bf16x8*)&sB[cur][bc * (BKL * 2) + (((ks + kk) * 2) ^ ((bc & 7) << 4))];
      #pragma unroll
      for (int rt = 0; rt < 4; ++rt) {
        const int ar = rt * 16 + cl;
        const bf16x8 afr = *(const bf16x8*)&sA[cur][ar * (BKL * 2) + (((ks + kk) * 2) ^ ((ar & 7) << 4))];
        acc[rt] = __builtin_amdgcn_mfma_f32_16x16x32_bf16(afr, bfr, acc[rt], 0, 0, 0);
      }
    }
    __builtin_amdgcn_s_barrier();
    __builtin_amdgcn_sched_barrier(0);
  }

  const int col = blk * 128 + wv * 16 + cl;
  const float bo = bout[col];
  #pragma unroll
  for (int rt = 0; rt < 4; ++rt)
    #pragma unroll
    for (int rg = 0; rg < 4; ++rg) {
      const int row = rt * 16 + (lane >> 4) * 4 + rg;
      lbuf[(size_t)row * VV + col] = acc[rt][rg] + bo;
    }
}

// ---------------- quarter stats + per-quarter exact argmax recheck (round-6 proven) ----------------
__global__ __launch_bounds__(256) void k_sum(
    const float* __restrict__ lbuf, const float* __restrict__ wout,
    const float* __restrict__ bout, const float* __restrict__ hnew,
    float* __restrict__ mq, float* __restrict__ sq,
    float* __restrict__ qbestV, int* __restrict__ qbestI, int dorecheck) {
  __shared__ float srow[QS];
  __shared__ float red[4];
  __shared__ int icnt;
  __shared__ int scand[32];
  const int tid = threadIdx.x;
  const int b = blockIdx.x >> 2, q = blockIdx.x & 3;
  const int lane = tid & 63, wv = tid >> 6;
  const f32x4* src = (const f32x4*)(lbuf + (size_t)b * VV + q * QS);
  f32x4* s4 = (f32x4*)srow;

  float m = -3.0e38f;
  for (int i = tid; i < QS / 4; i += 256) {
    const f32x4 v = src[i];
    s4[i] = v;
    m = fmaxf(fmaxf(fmaxf(m, v[0]), v[1]), fmaxf(v[2], v[3]));
  }
  #pragma unroll
  for (int d = 1; d < 64; d <<= 1) m = fmaxf(m, __shfl_xor(m, d, 64));
  if (lane == 0) red[wv] = m;
  if (tid == 0) icnt = 0;
  __syncthreads();
  const float M = fmaxf(fmaxf(red[0], red[1]), fmaxf(red[2], red[3]));

  float s = 0.f;
  for (int i = tid; i < QS / 4; i += 256) {
    const f32x4 v = s4[i];
    s += __expf(v[0] - M) + __expf(v[1] - M) + __expf(v[2] - M) + __expf(v[3] - M);
  }
  #pragma unroll
  for (int d = 1; d < 64; d <<= 1) s += __shfl_xor(s, d, 64);
  __syncthreads();
  if (lane == 0) red[wv] = s;
  __syncthreads();
  if (tid == 0) {
    mq[b * 4 + q] = M;
    sq[b * 4 + q] = red[0] + red[1] + red[2] + red[3];
  }

  if (dorecheck) {
    const float thr = M - 0.05f;
    for (int i = tid; i < QS / 4; i += 256) {
      const f32x4 v = s4[i];
      #pragma unroll
      for (int u = 0; u < 4; ++u)
        if (v[u] >= thr) {
          const int c = atomicAdd(&icnt, 1);
          if (c < 32) scand[c] = q * QS + 4 * i + u;
        }
    }
    __syncthreads();
    if (wv == 0) {
      const int nc = icnt < 32 ? icnt : 32;
      const float* hrow = hnew + (size_t)b * HH;
      f32x4 h4[4];
      #pragma unroll
      for (int u = 0; u < 4; ++u) h4[u] = *(const f32x4*)(hrow + lane * 16 + u * 4);
      float best = -3.0e38f; int bi = 0x7fffffff;
      for (int ci = 0; ci < nc; ++ci) {
        const int v = scand[ci];
        const float* wrow = wout + (size_t)v * HH + lane * 16;
        float ss = 0.f;
        #pragma unroll
        for (int u = 0; u < 4; ++u) {
          const f32x4 w4 = *(const f32x4*)(wrow + u * 4);
          ss += h4[u][0] * w4[0] + h4[u][1] * w4[1] + h4[u][2] * w4[2] + h4[u][3] * w4[3];
        }
        #pragma unroll
        for (int d = 1; d < 64; d <<= 1) ss += __shfl_xor(ss, d, 64);
        ss += bout[v];
        if (ss > best || (ss == best && v < bi)) { best = ss; bi = v; }
      }
      if (lane == 0) { qbestV[b * 4 + q] = best; qbestI[b * 4 + q] = bi; }
    }
  }
}

// ---------------- finalize: out for t=12 + h_final ----------------
__global__ __launch_bounds__(256) void k_fin(
    const float* __restrict__ lbufLast, const float* __restrict__ mq,
    const float* __restrict__ sq, const float* __restrict__ hfin,
    float* __restrict__ out) {
  __shared__ float lz[BB];
  const int tid = threadIdx.x;
  const int gid = blockIdx.x * 256 + tid;
  if (tid < BB) {
    const int b = tid;
    const float m0 = mq[b * 4 + 0], m1 = mq[b * 4 + 1];
    const float m2 = mq[b * 4 + 2], m3 = mq[b * 4 + 3];
    const float Mg = fmaxf(fmaxf(m0, m1), fmaxf(m2, m3));
    const float Sg = sq[b * 4 + 0] * __expf(m0 - Mg) + sq[b * 4 + 1] * __expf(m1 - Mg) +
                     sq[b * 4 + 2] * __expf(m2 - Mg) + sq[b * 4 + 3] * __expf(m3 - Mg);
    lz[b] = Mg + logf(Sg);
  }
  __syncthreads();
  const f32x4* src = (const f32x4*)lbufLast;
  for (int i4 = gid; i4 < BB * VV / 4; i4 += 65536) {
    const int b = i4 / (VV / 4);
    const f32x4 v = src[i4];
    ((f32x4*)out)[(size_t)(b * TT + (TT - 1)) * (VV / 4) + (i4 - b * (VV / 4))] = v - lz[b];
  }
  out[(size_t)BB * TT * VV + gid] = hfin[gid];
}

// ================= fallback path (ws too small) — round-6 proven =================
__global__ __launch_bounds__(64) void k_gru_fb(
    const unsigned short* __restrict__ xhi, const unsigned short* __restrict__ xlo,
    const unsigned short* __restrict__ hhi_s, const unsigned short* __restrict__ hlo_s,
    const float* __restrict__ wih, const float* __restrict__ whh,
    float* __restrict__ gbuf) {
  const int blk = blockIdx.x, lane = threadIdx.x;
  const int kh = blk & 1;
  const int r2 = blk >> 1;
  const int g6 = r2 % 6, jt = r2 / 6;
  const unsigned short* Ahi = g6 < 3 ? xhi : hhi_s;
  const unsigned short* Alo = g6 < 3 ? xlo : hlo_s;
  const int cl = lane & 15, kk = (lane >> 4) * 8;
  const int j = jt * 16 + cl;
  const int kbeg = kh * 512;
  f32x4 acc[4];
  acc[0] = acc[1] = acc[2] = acc[3] = (f32x4){0.f, 0.f, 0.f, 0.f};
  const float* W = (g6 < 3 ? wih : whh) + (size_t)((g6 % 3) * HH + j) * HH + kbeg;
  for (int k0 = 0; k0 < 512; k0 += 32) {
    const f32x4 w0 = *(const f32x4*)(W + k0 + kk);
    const f32x4 w1 = *(const f32x4*)(W + k0 + kk + 4);
    union { unsigned short u[8]; bf16x8 b; } chi, clo;
    #pragma unroll
    for (int u2 = 0; u2 < 4; ++u2) {
      chi.u[u2] = f2bf(w0[u2]); clo.u[u2] = f2bf(w0[u2] - bf2f(chi.u[u2]));
      chi.u[4 + u2] = f2bf(w1[u2]); clo.u[4 + u2] = f2bf(w1[u2] - bf2f(chi.u[4 + u2]));
    }
    #pragma unroll
    for (int rt = 0; rt < 4; ++rt) {
      const size_t aoff = (size_t)(rt * 16 + cl) * HH + kbeg + k0 + kk;
      const bf16x8 a_h = *(const bf16x8*)(Ahi + aoff);
      const bf16x8 a_l = *(const bf16x8*)(Alo + aoff);
      acc[rt] = __builtin_amdgcn_mfma_f32_16x16x32_bf16(a_h, chi.b, acc[rt], 0, 0, 0);
      acc[rt] = __builtin_amdgcn_mfma_f32_16x16x32_bf16(a_l, chi.b, acc[rt], 0, 0, 0);
      acc[rt] = __builtin_amdgcn_mfma_f32_16x16x32_bf16(a_h, clo.b, acc[rt], 0, 0, 0);
    }
  }
  #pragma unroll
  for (int rt = 0; rt < 4; ++rt)
    #pragma unroll
    for (int rg = 0; rg < 4; ++rg) {
      const int row = rt * 16 + (lane >> 4) * 4 + rg;
      gbuf[(size_t)((kh * 6 + g6) * BB + row) * HH + jt * 16 + cl] = acc[rt][rg];
    }
}

__global__ __launch_bounds__(256) void k_gep_fb(
    const float* __restrict__ gbuf, const float* __restrict__ bih,
    const float* __restrict__ bhh, const float* __restrict__ hsrc,
    float* __restrict__ hdst, unsigned short* __restrict__ hhi_d,
    unsigned short* __restrict__ hlo_d) {
  const int e = blockIdx.x * 256 + threadIdx.x;
  const int b = e >> 10, j = e & (HH - 1);
  const size_t base = (size_t)b * HH + j;
  const float gir = gbuf[(size_t)(0 * BB + b) * HH + j] + gbuf[(size_t)((6 + 0) * BB + b) * HH + j] + bih[j];
  const float giz = gbuf[(size_t)(1 * BB + b) * HH + j] + gbuf[(size_t)((6 + 1) * BB + b) * HH + j] + bih[HH + j];
  const float gin = gbuf[(size_t)(2 * BB + b) * HH + j] + gbuf[(size_t)((6 + 2) * BB + b) * HH + j] + bih[2 * HH + j];
  const float ghr = gbuf[(size_t)(3 * BB + b) * HH + j] + gbuf[(size_t)((6 + 3) * BB + b) * HH + j] + bhh[j];
  const float ghz = gbuf[(size_t)(4 * BB + b) * HH + j] + gbuf[(size_t)((6 + 4) * BB + b) * HH + j] + bhh[HH + j];
  const float ghn = gbuf[(size_t)(5 * BB + b) * HH + j] + gbuf[(size_t)((6 + 5) * BB + b) * HH + j] + bhh[2 * HH + j];
  const float r_ = 1.f / (1.f + __expf(-(gir + ghr)));
  const float z_ = 1.f / (1.f + __expf(-(giz + ghz)));
  const float n_ = tanhf(gin + r_ * ghn);
  const float hnew = (1.f - z_) * n_ + z_ * hsrc[base];
  hdst[base] = hnew;
  const unsigned short h16 = f2bf(hnew);
  hhi_d[base] = h16;
  hlo_d[base] = f2bf(hnew - bf2f(h16));
}

__global__ __launch_bounds__(256) void k_logits_fb(
    const unsigned short* __restrict__ hb, const float* __restrict__ wout,
    const float* __restrict__ bout, float* __restrict__ lbuf) {
  const int tid = threadIdx.x, blk = blockIdx.x;
  const int lane = tid & 63, wv = tid >> 6;
  const int n0 = blk * 64 + wv * 16;
  const int cl = lane & 15, kk = (lane >> 4) * 8;
  f32x4 acc[4];
  acc[0] = acc[1] = acc[2] = acc[3] = (f32x4){0.f, 0.f, 0.f, 0.f};
  const float* wrow = wout + (size_t)(n0 + cl) * HH;
  for (int k0 = 0; k0 < HH; k0 += 32) {
    const f32x4 w0 = *(const f32x4*)(wrow + k0 + kk);
    const f32x4 w1 = *(const f32x4*)(wrow + k0 + kk + 4);
    union { unsigned short u[8]; bf16x8 b; } cv;
    #pragma unroll
    for (int u2 = 0; u2 < 4; ++u2) { cv.u[u2] = f2bf(w0[u2]); cv.u[4 + u2] = f2bf(w1[u2]); }
    #pragma unroll
    for (int rt = 0; rt < 4; ++rt) {
      const bf16x8 afr = *(const bf16x8*)(hb + (size_t)(rt * 16 + cl) * HH + k0 + kk);
      acc[rt] = __builtin_amdgcn_mfma_f32_16x16x32_bf16(afr, cv.b, acc[rt], 0, 0, 0);
    }
  }
  const int col = n0 + cl;
  const float bo = bout[col];
  #pragma unroll
  for (int rt = 0; rt < 4; ++rt)
    #pragma unroll
    for (int rg = 0; rg < 4; ++rg) {
      const int row = rt * 16 + (lane >> 4) * 4 + rg;
      lbuf[(size_t)row * VV + col] = acc[rt][rg] + bo;
    }
}

__global__ __launch_bounds__(256) void k_out_fb(
    const float* __restrict__ lbuf, const float* __restrict__ mq,
    const float* __restrict__ sq, const float* __restrict__ qbestV,
    const int* __restrict__ qbestI, const float* __restrict__ emb,
    const float* __restrict__ hnew, float* __restrict__ out,
    unsigned short* __restrict__ xhi, unsigned short* __restrict__ xlo, int t) {
  __shared__ int stok;
  const int tid = threadIdx.x;
  const int b = blockIdx.x >> 2, q = blockIdx.x & 3;
  const float m0 = mq[b * 4 + 0], m1 = mq[b * 4 + 1];
  const float m2 = mq[b * 4 + 2], m3 = mq[b * 4 + 3];
  const float Mg = fmaxf(fmaxf(m0, m1), fmaxf(m2, m3));
  const float Sg = sq[b * 4 + 0] * __expf(m0 - Mg) + sq[b * 4 + 1] * __expf(m1 - Mg) +
                   sq[b * 4 + 2] * __expf(m2 - Mg) + sq[b * 4 + 3] * __expf(m3 - Mg);
  const float LZ = Mg + logf(Sg);
  const f32x4* src = (const f32x4*)(lbuf + (size_t)b * VV + q * QS);
  f32x4* dst = (f32x4*)(out + ((size_t)b * TT + t) * VV + q * QS);
  for (int i = tid; i < QS / 4; i += 256)
    dst[i] = src[i] - LZ;
  if (q == 0 && t < TT - 1) {
    if (tid == 0) {
      float bv = qbestV[b * 4 + 0]; int bi = qbestI[b * 4 + 0];
      #pragma unroll
      for (int qq = 1; qq < 4; ++qq) {
        const float v = qbestV[b * 4 + qq]; const int i2 = qbestI[b * 4 + qq];
        if (v > bv || (v == bv && i2 < bi)) { bv = v; bi = i2; }
      }
      stok = bi;
    }
    __syncthreads();
    const int tok = stok;
    for (int j = tid; j < HH; j += 256) {
      float e = emb[(size_t)tok * HH + j];
      e = e > 0.f ? e : 0.f;
      const unsigned short e16 = f2bf(e);
      xhi[(size_t)b * HH + j] = e16;
      xlo[(size_t)b * HH + j] = f2bf(e - bf2f(e16));
    }
  }
  if (q == 0 && t == TT - 1) {
    for (int j = tid; j < HH; j += 256)
      out[(size_t)BB * TT * VV + (size_t)b * HH + j] = hnew[(size_t)b * HH + j];
  }
}

extern "C" void kernel_launch(void* const* d_in, const int* in_sizes, int n_in,
                              void* d_out, int out_size, void* d_ws, size_t ws_size,
                              hipStream_t stream) {
  const float* enc  = (const float*)d_in[1];
  const float* emb  = (const float*)d_in[2];
  const float* wih  = (const float*)d_in[3];
  const float* whh  = (const float*)d_in[4];
  const float* bih  = (const float*)d_in[5];
  const float* bhh  = (const float*)d_in[6];
  const float* wout = (const float*)d_in[7];
  const float* bout = (const float*)d_in[8];
  float* out = (float*)d_out;

  char* ws = (char*)d_ws;
  size_t off = 0;
  auto alloc = [&](size_t bytes) -> char* {
    char* p = ws + off;
    off += (bytes + 255) & ~(size_t)255;
    return p;
  };
  float* hrm = (float*)alloc((size_t)2 * BB * HH * 4);
  unsigned short* hhi = (unsigned short*)alloc((size_t)2 * BB * HH * 2);
  unsigned short* hlo = (unsigned short*)alloc((size_t)2 * BB * HH * 2);
  unsigned short* xhi = (unsigned short*)alloc((size_t)BB * HH * 2);
  unsigned short* xlo = (unsigned short*)alloc((size_t)BB * HH * 2);
  float* gbuf = (float*)alloc((size_t)12 * BB * HH * 4);
  float* lbuf = (float*)alloc((size_t)2 * BB * VV * 4);   // double-buffered
  float* mq = (float*)alloc((size_t)BB * 4 * 4);
  float* sq = (float*)alloc((size_t)BB * 4 * 4);
  float* qbestV = (float*)alloc((size_t)BB * 4 * 4);
  int* qbestI = (int*)alloc((size_t)BB * 4 * 4);
  unsigned short* wbf = (unsigned short*)alloc((size_t)VV * HH * 2);
  unsigned short* ghi = (unsigned short*)alloc((size_t)6 * HH * HH * 2);
  unsigned short* glo = (unsigned short*)alloc((size_t)6 * HH * HH * 2);
  const int cache_ok = (ws_size >= off) ? 1 : 0;

  hipLaunchKernelGGL(k_init, dim3(64), dim3(1024), 0, stream,
                     enc, emb, hrm, hhi, hlo, xhi, xlo);
  if (cache_ok) {
    hipLaunchKernelGGL(k_wconv, dim3(2048), dim3(256), 0, stream, wout, wbf);
    hipLaunchKernelGGL(k_wconv2, dim3(1024), dim3(256), 0, stream, wih, whh, ghi, glo);

    for (int t = 0; t < TT; ++t) {
      const int p = t & 1;
      const float* hsrc = hrm + (size_t)p * BB * HH;
      float* hdst = hrm + (size_t)(p ^ 1) * BB * HH;
      const unsigned short* hhs = hhi + (size_t)p * BB * HH;
      const unsigned short* hls = hlo + (size_t)p * BB * HH;
      unsigned short* hhd = hhi + (size_t)(p ^ 1) * BB * HH;
      unsigned short* hld = hlo + (size_t)(p ^ 1) * BB * HH;
      float* lb = lbuf + (size_t)(t & 1) * BB * VV;
      const float* lbPrev = lbuf + (size_t)((t & 1) ^ 1) * BB * VV;

      hipLaunchKernelGGL(k_gru, dim3(768), dim3(64), 0, stream,
                         emb, hhs, hls, ghi, glo, qbestV, qbestI,
                         gbuf, (t > 0) ? 1 : 0);
      hipLaunchKernelGGL(k_gepO, dim3(256), dim3(256), 0, stream,
                         gbuf, bih, bhh, hsrc, hdst, hhd, hld,
                         lbPrev, mq, sq, out, t);
      hipLaunchKernelGGL(k_logits_lds, dim3(250), dim3(512), 0, stream,
                         hhd, wbf, bout, lb);
      hipLaunchKernelGGL(k_sum, dim3(256), dim3(256), 0, stream,
                         lb, wout, bout, hdst, mq, sq, qbestV, qbestI,
                         (t < TT - 1) ? 1 : 0);
    }
    hipLaunchKernelGGL(k_fin, dim3(256), dim3(256), 0, stream,
                       lbuf + (size_t)((TT - 1) & 1) * BB * VV, mq, sq,
                       hrm + (size_t)BB * HH, out);
  } else {
    float* lb0 = lbuf;
    for (int t = 0; t < TT; ++t) {
      const int p = t & 1;
      const float* hsrc = hrm + (size_t)p * BB * HH;
      float* hdst = hrm + (size_t)(p ^ 1) * BB * HH;
      const unsigned short* hhs = hhi + (size_t)p * BB * HH;
      const unsigned short* hls = hlo + (size_t)p * BB * HH;
      unsigned short* hhd = hhi + (size_t)(p ^ 1) * BB * HH;
      unsigned short* hld = hlo + (size_t)(p ^ 1) * BB * HH;
      hipLaunchKernelGGL(k_gru_fb, dim3(768), dim3(64), 0, stream,
                         xhi, xlo, hhs, hls, wih, whh, gbuf);
      hipLaunchKernelGGL(k_gep_fb, dim3(256), dim3(256), 0, stream,
                         gbuf, bih, bhh, hsrc, hdst, hhd, hld);
      hipLaunchKernelGGL(k_logits_fb, dim3(500), dim3(256), 0, stream,
                         hhd, wout, bout, lb0);
      hipLaunchKernelGGL(k_sum, dim3(256), dim3(256), 0, stream,
                         lb0, wout, bout, hdst, mq, sq, qbestV, qbestI,
                         (t < TT - 1) ? 1 : 0);
      hipLaunchKernelGGL(k_out_fb, dim3(256), dim3(256), 0, stream,
                         lb0, mq, sq, qbestV, qbestI, emb, hdst, out, xhi, xlo, t);
    }
  }
}

// Round 14
// 966.236 us; speedup vs baseline: 1.4436x; 1.0569x over previous
//
#include <hip/hip_runtime.h>
#include <math.h>

#define BB 64
#define HH 1024
#define VV 32000
#define TT 13
#define QS 8000            // VV/4 per quarter
#define BKL 128            // K-tile for staged logits GEMM

typedef float f32x4 __attribute__((ext_vector_type(4)));
typedef __bf16 bf16x8 __attribute__((ext_vector_type(8)));

__device__ __forceinline__ unsigned short f2bf(float f) {   // RNE
  unsigned u = __float_as_uint(f);
  u = (u + 0x7fffu + ((u >> 16) & 1u)) >> 16;
  return (unsigned short)u;
}
__device__ __forceinline__ float bf2f(unsigned short s) {
  return __uint_as_float(((unsigned)s) << 16);
}

// async global->LDS, 16B per lane
__device__ __forceinline__ void gld16(const void* g, void* l) {
  __builtin_amdgcn_global_load_lds(
      (const __attribute__((address_space(1))) unsigned int*)g,
      (__attribute__((address_space(3))) unsigned int*)l, 16, 0, 0);
}

// ---------------- init: h0 + splits; x0 -> xcand quarter 0 (and fallback bufs) ----------------
__global__ __launch_bounds__(1024) void k_init(
    const float* __restrict__ enc, const float* __restrict__ emb,
    float* __restrict__ hrm, unsigned short* __restrict__ hhi,
    unsigned short* __restrict__ hlo,
    unsigned short* __restrict__ xhi_c, unsigned short* __restrict__ xlo_c,
    unsigned short* __restrict__ xhi0, unsigned short* __restrict__ xlo0) {
  const int b = blockIdx.x, tid = threadIdx.x;
  const int g = b * 1024 + tid;
  const float h = enc[g];
  hrm[g] = h;
  const unsigned short h16 = f2bf(h);
  hhi[g] = h16;
  hlo[g] = f2bf(h - bf2f(h16));
  float e = emb[tid];                              // token 0 row
  e = e > 0.f ? e : 0.f;
  const unsigned short e16 = f2bf(e);
  const unsigned short el16 = f2bf(e - bf2f(e16));
  xhi_c[(size_t)(b * 4 + 0) * HH + tid] = e16;     // quarter-0 slot for t=0
  xlo_c[(size_t)(b * 4 + 0) * HH + tid] = el16;
  xhi0[g] = e16;                                   // fallback path buffers
  xlo0[g] = el16;
}

// ---------------- per-call: w_out -> bf16 (round-6 proven) ----------------
__global__ __launch_bounds__(256) void k_wconv(const float* __restrict__ w,
                                               unsigned short* __restrict__ o) {
  const int n4 = VV * HH / 4;
  for (int i = blockIdx.x * 256 + threadIdx.x; i < n4; i += gridDim.x * 256) {
    const f32x4 v = ((const f32x4*)w)[i];
    ushort4 u;
    u.x = f2bf(v[0]); u.y = f2bf(v[1]); u.z = f2bf(v[2]); u.w = f2bf(v[3]);
    ((ushort4*)o)[i] = u;
  }
}

// ---------------- per-call: wih/whh -> bf16 hi/lo split (round-6 proven) ----------------
__global__ __launch_bounds__(256) void k_wconv2(
    const float* __restrict__ wih, const float* __restrict__ whh,
    unsigned short* __restrict__ ghi, unsigned short* __restrict__ glo) {
  const int n4 = 6 * HH * HH / 4;
  for (int i = blockIdx.x * 256 + threadIdx.x; i < n4; i += gridDim.x * 256) {
    const int flat = i * 4;
    const float* src = flat < 3 * HH * HH ? wih + flat : whh + (flat - 3 * HH * HH);
    const f32x4 v = *(const f32x4*)src;
    ushort4 hi, lo;
    hi.x = f2bf(v[0]); lo.x = f2bf(v[0] - bf2f(hi.x));
    hi.y = f2bf(v[1]); lo.y = f2bf(v[1] - bf2f(hi.y));
    hi.z = f2bf(v[2]); lo.z = f2bf(v[2] - bf2f(hi.z));
    hi.w = f2bf(v[3]); lo.w = f2bf(v[3] - bf2f(hi.w));
    ((ushort4*)ghi)[i] = hi;
    ((ushort4*)glo)[i] = lo;
  }
}

// ---------------- GRU gates: 768 one-wave blocks; ih picks winning xcand quarter ----------------
// Pure bf16 inner loop (round-6 identical). Preamble only resolves quarter index.
__global__ __launch_bounds__(64) void k_gru(
    const unsigned short* __restrict__ xhi_c, const unsigned short* __restrict__ xlo_c,
    const unsigned short* __restrict__ hhi_s, const unsigned short* __restrict__ hlo_s,
    const unsigned short* __restrict__ ghi, const unsigned short* __restrict__ glo,
    const float* __restrict__ qbestV, const int* __restrict__ qbestI,
    float* __restrict__ gbuf, int use_qbest) {
  __shared__ int squart[64];
  const int blk = blockIdx.x, lane = threadIdx.x;
  const int kh = blk & 1;
  const int r2 = blk >> 1;
  const int g6 = r2 % 6, jt = r2 / 6;
  const int cl = lane & 15, kk = (lane >> 4) * 8;
  const int j = jt * 16 + cl;
  const int kbeg = kh * 512;
  const bool ih = g6 < 3;

  if (ih) {                                        // winning quarter for b = lane
    int qw = 0;
    if (use_qbest) {
      float bv = qbestV[lane * 4 + 0]; int bi = qbestI[lane * 4 + 0];
      #pragma unroll
      for (int qq = 1; qq < 4; ++qq) {
        const float v = qbestV[lane * 4 + qq]; const int i2 = qbestI[lane * 4 + qq];
        if (v > bv || (v == bv && i2 < bi)) { bv = v; bi = i2; qw = qq; }
      }
    }
    squart[lane] = qw;
  }
  __syncthreads();

  size_t abase[4];
  #pragma unroll
  for (int rt = 0; rt < 4; ++rt) {
    const int row = rt * 16 + cl;
    abase[rt] = (ih ? (size_t)(row * 4 + squart[row]) : (size_t)row) * HH + kbeg + kk;
  }
  const unsigned short* Ahi = ih ? xhi_c : hhi_s;
  const unsigned short* Alo = ih ? xlo_c : hlo_s;
  const unsigned short* bh = ghi + (size_t)(g6 * HH + j) * HH + kbeg;
  const unsigned short* bl = glo + (size_t)(g6 * HH + j) * HH + kbeg;

  f32x4 acc[4];
  acc[0] = acc[1] = acc[2] = acc[3] = (f32x4){0.f, 0.f, 0.f, 0.f};
  #pragma unroll 4
  for (int k0 = 0; k0 < 512; k0 += 32) {
    const bf16x8 whi = *(const bf16x8*)(bh + k0 + kk);
    const bf16x8 wlo = *(const bf16x8*)(bl + k0 + kk);
    #pragma unroll
    for (int rt = 0; rt < 4; ++rt) {
      const bf16x8 a_h = *(const bf16x8*)(Ahi + abase[rt] + k0);
      const bf16x8 a_l = *(const bf16x8*)(Alo + abase[rt] + k0);
      acc[rt] = __builtin_amdgcn_mfma_f32_16x16x32_bf16(a_h, whi, acc[rt], 0, 0, 0);
      acc[rt] = __builtin_amdgcn_mfma_f32_16x16x32_bf16(a_l, whi, acc[rt], 0, 0, 0);
      acc[rt] = __builtin_amdgcn_mfma_f32_16x16x32_bf16(a_h, wlo, acc[rt], 0, 0, 0);
    }
  }
  #pragma unroll
  for (int rt = 0; rt < 4; ++rt)
    #pragma unroll
    for (int rg = 0; rg < 4; ++rg) {
      const int row = rt * 16 + (lane >> 4) * 4 + rg;
      gbuf[(size_t)((kh * 6 + g6) * BB + row) * HH + jt * 16 + cl] = acc[rt][rg];
    }
}

// ---------------- GRU epilogue + prev-step out-write (r9 fusion) ----------------
__global__ __launch_bounds__(256) void k_gepO(
    const float* __restrict__ gbuf, const float* __restrict__ bih,
    const float* __restrict__ bhh, const float* __restrict__ hsrc,
    float* __restrict__ hdst, unsigned short* __restrict__ hhi_d,
    unsigned short* __restrict__ hlo_d,
    const float* __restrict__ lbufPrev, const float* __restrict__ mq,
    const float* __restrict__ sq, float* __restrict__ out, int t) {
  __shared__ float lz[BB];
  const int tid = threadIdx.x;
  const int gid = blockIdx.x * 256 + tid;
  if (t > 0 && tid < BB) {
    const int b = tid;
    const float m0 = mq[b * 4 + 0], m1 = mq[b * 4 + 1];
    const float m2 = mq[b * 4 + 2], m3 = mq[b * 4 + 3];
    const float Mg = fmaxf(fmaxf(m0, m1), fmaxf(m2, m3));
    const float Sg = sq[b * 4 + 0] * __expf(m0 - Mg) + sq[b * 4 + 1] * __expf(m1 - Mg) +
                     sq[b * 4 + 2] * __expf(m2 - Mg) + sq[b * 4 + 3] * __expf(m3 - Mg);
    lz[b] = Mg + logf(Sg);
  }
  __syncthreads();
  {
    const int b = gid >> 10, j = gid & (HH - 1);
    const size_t base = (size_t)b * HH + j;
    const float gir = gbuf[(size_t)(0 * BB + b) * HH + j] + gbuf[(size_t)((6 + 0) * BB + b) * HH + j] + bih[j];
    const float giz = gbuf[(size_t)(1 * BB + b) * HH + j] + gbuf[(size_t)((6 + 1) * BB + b) * HH + j] + bih[HH + j];
    const float gin = gbuf[(size_t)(2 * BB + b) * HH + j] + gbuf[(size_t)((6 + 2) * BB + b) * HH + j] + bih[2 * HH + j];
    const float ghr = gbuf[(size_t)(3 * BB + b) * HH + j] + gbuf[(size_t)((6 + 3) * BB + b) * HH + j] + bhh[j];
    const float ghz = gbuf[(size_t)(4 * BB + b) * HH + j] + gbuf[(size_t)((6 + 4) * BB + b) * HH + j] + bhh[HH + j];
    const float ghn = gbuf[(size_t)(5 * BB + b) * HH + j] + gbuf[(size_t)((6 + 5) * BB + b) * HH + j] + bhh[2 * HH + j];
    const float r_ = 1.f / (1.f + __expf(-(gir + ghr)));
    const float z_ = 1.f / (1.f + __expf(-(giz + ghz)));
    const float n_ = tanhf(gin + r_ * ghn);
    const float hnew = (1.f - z_) * n_ + z_ * hsrc[base];
    hdst[base] = hnew;
    const unsigned short h16 = f2bf(hnew);
    hhi_d[base] = h16;
    hlo_d[base] = f2bf(hnew - bf2f(h16));
  }
  if (t > 0) {
    const f32x4* src = (const f32x4*)lbufPrev;
    for (int i4 = gid; i4 < BB * VV / 4; i4 += 65536) {
      const int b = i4 / (VV / 4);
      const f32x4 v = src[i4];
      ((f32x4*)out)[(size_t)(b * TT + (t - 1)) * (VV / 4) + (i4 - b * (VV / 4))] = v - lz[b];
    }
  }
}

// ---------------- logits: staged GEMM (round-6 proven, untouched) ----------------
__global__ __launch_bounds__(512, 1) void k_logits_lds(
    const unsigned short* __restrict__ hb,
    const unsigned short* __restrict__ wbf,
    const float* __restrict__ bout, float* __restrict__ lbuf) {
  __shared__ __attribute__((aligned(16))) unsigned char sA[2][64 * BKL * 2];
  __shared__ __attribute__((aligned(16))) unsigned char sB[2][128 * BKL * 2];
  const int tid = threadIdx.x, blk = blockIdx.x;
  const int lane = tid & 63, wv = tid >> 6;
  const int cl = lane & 15, kk = (lane >> 4) * 8;

  auto STAGE = [&](int buf, int k0) {
    #pragma unroll
    for (int it = 0; it < 2; ++it) {
      const int c = it * 512 + tid;
      const int r = c >> 4;
      const int kb = (c & 15) * 16;
      const int kbs = kb ^ ((r & 7) << 4);
      gld16(hb + (size_t)r * HH + k0 + (kbs >> 1),
            &sA[buf][it * 8192 + wv * 1024]);
    }
    #pragma unroll
    for (int it = 0; it < 4; ++it) {
      const int c = it * 512 + tid;
      const int col = c >> 4;
      const int kb = (c & 15) * 16;
      const int kbs = kb ^ ((col & 7) << 4);
      gld16(wbf + (size_t)(blk * 128 + col) * HH + k0 + (kbs >> 1),
            &sB[buf][it * 8192 + wv * 1024]);
    }
  };

  f32x4 acc[4];
  acc[0] = acc[1] = acc[2] = acc[3] = (f32x4){0.f, 0.f, 0.f, 0.f};

  STAGE(0, 0);
  for (int t = 0; t < HH / BKL; ++t) {
    const int cur = t & 1;
    if (t < HH / BKL - 1) {
      STAGE(cur ^ 1, (t + 1) * BKL);
      asm volatile("s_waitcnt vmcnt(6)" ::: "memory");
    } else {
      asm volatile("s_waitcnt vmcnt(0)" ::: "memory");
    }
    __builtin_amdgcn_s_barrier();
    __builtin_amdgcn_sched_barrier(0);
    #pragma unroll
    for (int ks = 0; ks < BKL; ks += 32) {
      const int bc = wv * 16 + cl;
      const bf16x8 bfr = *(const bf16x8*)&sB[cur][bc * (BKL * 2) + (((ks + kk) * 2) ^ ((bc & 7) << 4))];
      #pragma unroll
      for (int rt = 0; rt < 4; ++rt) {
        const int ar = rt * 16 + cl;
        const bf16x8 afr = *(const bf16x8*)&sA[cur][ar * (BKL * 2) + (((ks + kk) * 2) ^ ((ar & 7) << 4))];
        acc[rt] = __builtin_amdgcn_mfma_f32_16x16x32_bf16(afr, bfr, acc[rt], 0, 0, 0);
      }
    }
    __builtin_amdgcn_s_barrier();
    __builtin_amdgcn_sched_barrier(0);
  }

  const int col = blk * 128 + wv * 16 + cl;
  const float bo = bout[col];
  #pragma unroll
  for (int rt = 0; rt < 4; ++rt)
    #pragma unroll
    for (int rg = 0; rg < 4; ++rg) {
      const int row = rt * 16 + (lane >> 4) * 4 + rg;
      lbuf[(size_t)row * VV + col] = acc[rt][rg] + bo;
    }
}

// ---------------- quarter stats + exact recheck + per-quarter xcand write ----------------
__global__ __launch_bounds__(256) void k_sum(
    const float* __restrict__ lbuf, const float* __restrict__ wout,
    const float* __restrict__ bout, const float* __restrict__ hnew,
    const float* __restrict__ emb,
    float* __restrict__ mq, float* __restrict__ sq,
    float* __restrict__ qbestV, int* __restrict__ qbestI,
    unsigned short* __restrict__ xhi_c, unsigned short* __restrict__ xlo_c,
    int dorecheck) {
  __shared__ float srow[QS];
  __shared__ float red[4];
  __shared__ int icnt, sbi;
  __shared__ int scand[32];
  const int tid = threadIdx.x;
  const int b = blockIdx.x >> 2, q = blockIdx.x & 3;
  const int lane = tid & 63, wv = tid >> 6;
  const f32x4* src = (const f32x4*)(lbuf + (size_t)b * VV + q * QS);
  f32x4* s4 = (f32x4*)srow;

  float m = -3.0e38f;
  for (int i = tid; i < QS / 4; i += 256) {
    const f32x4 v = src[i];
    s4[i] = v;
    m = fmaxf(fmaxf(fmaxf(m, v[0]), v[1]), fmaxf(v[2], v[3]));
  }
  #pragma unroll
  for (int d = 1; d < 64; d <<= 1) m = fmaxf(m, __shfl_xor(m, d, 64));
  if (lane == 0) red[wv] = m;
  if (tid == 0) icnt = 0;
  __syncthreads();
  const float M = fmaxf(fmaxf(red[0], red[1]), fmaxf(red[2], red[3]));

  float s = 0.f;
  for (int i = tid; i < QS / 4; i += 256) {
    const f32x4 v = s4[i];
    s += __expf(v[0] - M) + __expf(v[1] - M) + __expf(v[2] - M) + __expf(v[3] - M);
  }
  #pragma unroll
  for (int d = 1; d < 64; d <<= 1) s += __shfl_xor(s, d, 64);
  __syncthreads();
  if (lane == 0) red[wv] = s;
  __syncthreads();
  if (tid == 0) {
    mq[b * 4 + q] = M;
    sq[b * 4 + q] = red[0] + red[1] + red[2] + red[3];
  }

  if (dorecheck) {
    const float thr = M - 0.05f;
    for (int i = tid; i < QS / 4; i += 256) {
      const f32x4 v = s4[i];
      #pragma unroll
      for (int u = 0; u < 4; ++u)
        if (v[u] >= thr) {
          const int c = atomicAdd(&icnt, 1);
          if (c < 32) scand[c] = q * QS + 4 * i + u;
        }
    }
    __syncthreads();
    if (wv == 0) {
      const int nc = icnt < 32 ? icnt : 32;
      const float* hrow = hnew + (size_t)b * HH;
      f32x4 h4[4];
      #pragma unroll
      for (int u = 0; u < 4; ++u) h4[u] = *(const f32x4*)(hrow + lane * 16 + u * 4);
      float best = -3.0e38f; int bi = 0x7fffffff;
      for (int ci = 0; ci < nc; ++ci) {
        const int v = scand[ci];
        const float* wrow = wout + (size_t)v * HH + lane * 16;
        float ss = 0.f;
        #pragma unroll
        for (int u = 0; u < 4; ++u) {
          const f32x4 w4 = *(const f32x4*)(wrow + u * 4);
          ss += h4[u][0] * w4[0] + h4[u][1] * w4[1] + h4[u][2] * w4[2] + h4[u][3] * w4[3];
        }
        #pragma unroll
        for (int d = 1; d < 64; d <<= 1) ss += __shfl_xor(ss, d, 64);
        ss += bout[v];
        if (ss > best || (ss == best && v < bi)) { best = ss; bi = v; }
      }
      if (lane == 0) { qbestV[b * 4 + q] = best; qbestI[b * 4 + q] = bi; sbi = bi; }
    }
    __syncthreads();
    // convert this quarter's candidate x row -> bf16 hi/lo (gru reads winner's)
    const int bi = sbi;
    const float* erow = emb + (size_t)bi * HH;
    unsigned short* xh = xhi_c + (size_t)(b * 4 + q) * HH;
    unsigned short* xl = xlo_c + (size_t)(b * 4 + q) * HH;
    for (int k = tid; k < HH / 4; k += 256) {
      f32x4 v = ((const f32x4*)erow)[k];
      ushort4 hi, lo;
      #pragma unroll
      for (int u = 0; u < 4; ++u) v[u] = v[u] > 0.f ? v[u] : 0.f;
      hi.x = f2bf(v[0]); lo.x = f2bf(v[0] - bf2f(hi.x));
      hi.y = f2bf(v[1]); lo.y = f2bf(v[1] - bf2f(hi.y));
      hi.z = f2bf(v[2]); lo.z = f2bf(v[2] - bf2f(hi.z));
      hi.w = f2bf(v[3]); lo.w = f2bf(v[3] - bf2f(hi.w));
      ((ushort4*)xh)[k] = hi;
      ((ushort4*)xl)[k] = lo;
    }
  }
}

// ---------------- finalize: out for t=12 + h_final ----------------
__global__ __launch_bounds__(256) void k_fin(
    const float* __restrict__ lbufLast, const float* __restrict__ mq,
    const float* __restrict__ sq, const float* __restrict__ hfin,
    float* __restrict__ out) {
  __shared__ float lz[BB];
  const int tid = threadIdx.x;
  const int gid = blockIdx.x * 256 + tid;
  if (tid < BB) {
    const int b = tid;
    const float m0 = mq[b * 4 + 0], m1 = mq[b * 4 + 1];
    const float m2 = mq[b * 4 + 2], m3 = mq[b * 4 + 3];
    const float Mg = fmaxf(fmaxf(m0, m1), fmaxf(m2, m3));
    const float Sg = sq[b * 4 + 0] * __expf(m0 - Mg) + sq[b * 4 + 1] * __expf(m1 - Mg) +
                     sq[b * 4 + 2] * __expf(m2 - Mg) + sq[b * 4 + 3] * __expf(m3 - Mg);
    lz[b] = Mg + logf(Sg);
  }
  __syncthreads();
  const f32x4* src = (const f32x4*)lbufLast;
  for (int i4 = gid; i4 < BB * VV / 4; i4 += 65536) {
    const int b = i4 / (VV / 4);
    const f32x4 v = src[i4];
    ((f32x4*)out)[(size_t)(b * TT + (TT - 1)) * (VV / 4) + (i4 - b * (VV / 4))] = v - lz[b];
  }
  out[(size_t)BB * TT * VV + gid] = hfin[gid];
}

// ================= fallback path (ws too small) — round-6 proven =================
__global__ __launch_bounds__(64) void k_gru_fb(
    const unsigned short* __restrict__ xhi, const unsigned short* __restrict__ xlo,
    const unsigned short* __restrict__ hhi_s, const unsigned short* __restrict__ hlo_s,
    const float* __restrict__ wih, const float* __restrict__ whh,
    float* __restrict__ gbuf) {
  const int blk = blockIdx.x, lane = threadIdx.x;
  const int kh = blk & 1;
  const int r2 = blk >> 1;
  const int g6 = r2 % 6, jt = r2 / 6;
  const unsigned short* Ahi = g6 < 3 ? xhi : hhi_s;
  const unsigned short* Alo = g6 < 3 ? xlo : hlo_s;
  const int cl = lane & 15, kk = (lane >> 4) * 8;
  const int j = jt * 16 + cl;
  const int kbeg = kh * 512;
  f32x4 acc[4];
  acc[0] = acc[1] = acc[2] = acc[3] = (f32x4){0.f, 0.f, 0.f, 0.f};
  const float* W = (g6 < 3 ? wih : whh) + (size_t)((g6 % 3) * HH + j) * HH + kbeg;
  for (int k0 = 0; k0 < 512; k0 += 32) {
    const f32x4 w0 = *(const f32x4*)(W + k0 + kk);
    const f32x4 w1 = *(const f32x4*)(W + k0 + kk + 4);
    union { unsigned short u[8]; bf16x8 b; } chi, clo;
    #pragma unroll
    for (int u2 = 0; u2 < 4; ++u2) {
      chi.u[u2] = f2bf(w0[u2]); clo.u[u2] = f2bf(w0[u2] - bf2f(chi.u[u2]));
      chi.u[4 + u2] = f2bf(w1[u2]); clo.u[4 + u2] = f2bf(w1[u2] - bf2f(chi.u[4 + u2]));
    }
    #pragma unroll
    for (int rt = 0; rt < 4; ++rt) {
      const size_t aoff = (size_t)(rt * 16 + cl) * HH + kbeg + k0 + kk;
      const bf16x8 a_h = *(const bf16x8*)(Ahi + aoff);
      const bf16x8 a_l = *(const bf16x8*)(Alo + aoff);
      acc[rt] = __builtin_amdgcn_mfma_f32_16x16x32_bf16(a_h, chi.b, acc[rt], 0, 0, 0);
      acc[rt] = __builtin_amdgcn_mfma_f32_16x16x32_bf16(a_l, chi.b, acc[rt], 0, 0, 0);
      acc[rt] = __builtin_amdgcn_mfma_f32_16x16x32_bf16(a_h, clo.b, acc[rt], 0, 0, 0);
    }
  }
  #pragma unroll
  for (int rt = 0; rt < 4; ++rt)
    #pragma unroll
    for (int rg = 0; rg < 4; ++rg) {
      const int row = rt * 16 + (lane >> 4) * 4 + rg;
      gbuf[(size_t)((kh * 6 + g6) * BB + row) * HH + jt * 16 + cl] = acc[rt][rg];
    }
}

__global__ __launch_bounds__(256) void k_gep_fb(
    const float* __restrict__ gbuf, const float* __restrict__ bih,
    const float* __restrict__ bhh, const float* __restrict__ hsrc,
    float* __restrict__ hdst, unsigned short* __restrict__ hhi_d,
    unsigned short* __restrict__ hlo_d) {
  const int e = blockIdx.x * 256 + threadIdx.x;
  const int b = e >> 10, j = e & (HH - 1);
  const size_t base = (size_t)b * HH + j;
  const float gir = gbuf[(size_t)(0 * BB + b) * HH + j] + gbuf[(size_t)((6 + 0) * BB + b) * HH + j] + bih[j];
  const float giz = gbuf[(size_t)(1 * BB + b) * HH + j] + gbuf[(size_t)((6 + 1) * BB + b) * HH + j] + bih[HH + j];
  const float gin = gbuf[(size_t)(2 * BB + b) * HH + j] + gbuf[(size_t)((6 + 2) * BB + b) * HH + j] + bih[2 * HH + j];
  const float ghr = gbuf[(size_t)(3 * BB + b) * HH + j] + gbuf[(size_t)((6 + 3) * BB + b) * HH + j] + bhh[j];
  const float ghz = gbuf[(size_t)(4 * BB + b) * HH + j] + gbuf[(size_t)((6 + 4) * BB + b) * HH + j] + bhh[HH + j];
  const float ghn = gbuf[(size_t)(5 * BB + b) * HH + j] + gbuf[(size_t)((6 + 5) * BB + b) * HH + j] + bhh[2 * HH + j];
  const float r_ = 1.f / (1.f + __expf(-(gir + ghr)));
  const float z_ = 1.f / (1.f + __expf(-(giz + ghz)));
  const float n_ = tanhf(gin + r_ * ghn);
  const float hnew = (1.f - z_) * n_ + z_ * hsrc[base];
  hdst[base] = hnew;
  const unsigned short h16 = f2bf(hnew);
  hhi_d[base] = h16;
  hlo_d[base] = f2bf(hnew - bf2f(h16));
}

__global__ __launch_bounds__(256) void k_logits_fb(
    const unsigned short* __restrict__ hb, const float* __restrict__ wout,
    const float* __restrict__ bout, float* __restrict__ lbuf) {
  const int tid = threadIdx.x, blk = blockIdx.x;
  const int lane = tid & 63, wv = tid >> 6;
  const int n0 = blk * 64 + wv * 16;
  const int cl = lane & 15, kk = (lane >> 4) * 8;
  f32x4 acc[4];
  acc[0] = acc[1] = acc[2] = acc[3] = (f32x4){0.f, 0.f, 0.f, 0.f};
  const float* wrow = wout + (size_t)(n0 + cl) * HH;
  for (int k0 = 0; k0 < HH; k0 += 32) {
    const f32x4 w0 = *(const f32x4*)(wrow + k0 + kk);
    const f32x4 w1 = *(const f32x4*)(wrow + k0 + kk + 4);
    union { unsigned short u[8]; bf16x8 b; } cv;
    #pragma unroll
    for (int u2 = 0; u2 < 4; ++u2) { cv.u[u2] = f2bf(w0[u2]); cv.u[4 + u2] = f2bf(w1[u2]); }
    #pragma unroll
    for (int rt = 0; rt < 4; ++rt) {
      const bf16x8 afr = *(const bf16x8*)(hb + (size_t)(rt * 16 + cl) * HH + k0 + kk);
      acc[rt] = __builtin_amdgcn_mfma_f32_16x16x32_bf16(afr, cv.b, acc[rt], 0, 0, 0);
    }
  }
  const int col = n0 + cl;
  const float bo = bout[col];
  #pragma unroll
  for (int rt = 0; rt < 4; ++rt)
    #pragma unroll
    for (int rg = 0; rg < 4; ++rg) {
      const int row = rt * 16 + (lane >> 4) * 4 + rg;
      lbuf[(size_t)row * VV + col] = acc[rt][rg] + bo;
    }
}

__global__ __launch_bounds__(256) void k_out_fb(
    const float* __restrict__ lbuf, const float* __restrict__ mq,
    const float* __restrict__ sq, const float* __restrict__ qbestV,
    const int* __restrict__ qbestI, const float* __restrict__ emb,
    const float* __restrict__ hnew, float* __restrict__ out,
    unsigned short* __restrict__ xhi, unsigned short* __restrict__ xlo, int t) {
  __shared__ int stok;
  const int tid = threadIdx.x;
  const int b = blockIdx.x >> 2, q = blockIdx.x & 3;
  const float m0 = mq[b * 4 + 0], m1 = mq[b * 4 + 1];
  const float m2 = mq[b * 4 + 2], m3 = mq[b * 4 + 3];
  const float Mg = fmaxf(fmaxf(m0, m1), fmaxf(m2, m3));
  const float Sg = sq[b * 4 + 0] * __expf(m0 - Mg) + sq[b * 4 + 1] * __expf(m1 - Mg) +
                   sq[b * 4 + 2] * __expf(m2 - Mg) + sq[b * 4 + 3] * __expf(m3 - Mg);
  const float LZ = Mg + logf(Sg);
  const f32x4* src = (const f32x4*)(lbuf + (size_t)b * VV + q * QS);
  f32x4* dst = (f32x4*)(out + ((size_t)b * TT + t) * VV + q * QS);
  for (int i = tid; i < QS / 4; i += 256)
    dst[i] = src[i] - LZ;
  if (q == 0 && t < TT - 1) {
    if (tid == 0) {
      float bv = qbestV[b * 4 + 0]; int bi = qbestI[b * 4 + 0];
      #pragma unroll
      for (int qq = 1; qq < 4; ++qq) {
        const float v = qbestV[b * 4 + qq]; const int i2 = qbestI[b * 4 + qq];
        if (v > bv || (v == bv && i2 < bi)) { bv = v; bi = i2; }
      }
      stok = bi;
    }
    __syncthreads();
    const int tok = stok;
    for (int j = tid; j < HH; j += 256) {
      float e = emb[(size_t)tok * HH + j];
      e = e > 0.f ? e : 0.f;
      const unsigned short e16 = f2bf(e);
      xhi[(size_t)b * HH + j] = e16;
      xlo[(size_t)b * HH + j] = f2bf(e - bf2f(e16));
    }
  }
  if (q == 0 && t == TT - 1) {
    for (int j = tid; j < HH; j += 256)
      out[(size_t)BB * TT * VV + (size_t)b * HH + j] = hnew[(size_t)b * HH + j];
  }
}

extern "C" void kernel_launch(void* const* d_in, const int* in_sizes, int n_in,
                              void* d_out, int out_size, void* d_ws, size_t ws_size,
                              hipStream_t stream) {
  const float* enc  = (const float*)d_in[1];
  const float* emb  = (const float*)d_in[2];
  const float* wih  = (const float*)d_in[3];
  const float* whh  = (const float*)d_in[4];
  const float* bih  = (const float*)d_in[5];
  const float* bhh  = (const float*)d_in[6];
  const float* wout = (const float*)d_in[7];
  const float* bout = (const float*)d_in[8];
  float* out = (float*)d_out;

  char* ws = (char*)d_ws;
  size_t off = 0;
  auto alloc = [&](size_t bytes) -> char* {
    char* p = ws + off;
    off += (bytes + 255) & ~(size_t)255;
    return p;
  };
  float* hrm = (float*)alloc((size_t)2 * BB * HH * 4);
  unsigned short* hhi = (unsigned short*)alloc((size_t)2 * BB * HH * 2);
  unsigned short* hlo = (unsigned short*)alloc((size_t)2 * BB * HH * 2);
  unsigned short* xhi_c = (unsigned short*)alloc((size_t)BB * 4 * HH * 2);
  unsigned short* xlo_c = (unsigned short*)alloc((size_t)BB * 4 * HH * 2);
  unsigned short* xhi0 = (unsigned short*)alloc((size_t)BB * HH * 2);
  unsigned short* xlo0 = (unsigned short*)alloc((size_t)BB * HH * 2);
  float* gbuf = (float*)alloc((size_t)12 * BB * HH * 4);
  float* lbuf = (float*)alloc((size_t)2 * BB * VV * 4);   // double-buffered
  float* mq = (float*)alloc((size_t)BB * 4 * 4);
  float* sq = (float*)alloc((size_t)BB * 4 * 4);
  float* qbestV = (float*)alloc((size_t)BB * 4 * 4);
  int* qbestI = (int*)alloc((size_t)BB * 4 * 4);
  unsigned short* wbf = (unsigned short*)alloc((size_t)VV * HH * 2);
  unsigned short* ghi = (unsigned short*)alloc((size_t)6 * HH * HH * 2);
  unsigned short* glo = (unsigned short*)alloc((size_t)6 * HH * HH * 2);
  const int cache_ok = (ws_size >= off) ? 1 : 0;

  hipLaunchKernelGGL(k_init, dim3(64), dim3(1024), 0, stream,
                     enc, emb, hrm, hhi, hlo, xhi_c, xlo_c, xhi0, xlo0);
  if (cache_ok) {
    hipLaunchKernelGGL(k_wconv, dim3(2048), dim3(256), 0, stream, wout, wbf);
    hipLaunchKernelGGL(k_wconv2, dim3(1024), dim3(256), 0, stream, wih, whh, ghi, glo);

    for (int t = 0; t < TT; ++t) {
      const int p = t & 1;
      const float* hsrc = hrm + (size_t)p * BB * HH;
      float* hdst = hrm + (size_t)(p ^ 1) * BB * HH;
      const unsigned short* hhs = hhi + (size_t)p * BB * HH;
      const unsigned short* hls = hlo + (size_t)p * BB * HH;
      unsigned short* hhd = hhi + (size_t)(p ^ 1) * BB * HH;
      unsigned short* hld = hlo + (size_t)(p ^ 1) * BB * HH;
      float* lb = lbuf + (size_t)(t & 1) * BB * VV;
      const float* lbPrev = lbuf + (size_t)((t & 1) ^ 1) * BB * VV;

      hipLaunchKernelGGL(k_gru, dim3(768), dim3(64), 0, stream,
                         xhi_c, xlo_c, hhs, hls, ghi, glo, qbestV, qbestI,
                         gbuf, (t > 0) ? 1 : 0);
      hipLaunchKernelGGL(k_gepO, dim3(256), dim3(256), 0, stream,
                         gbuf, bih, bhh, hsrc, hdst, hhd, hld,
                         lbPrev, mq, sq, out, t);
      hipLaunchKernelGGL(k_logits_lds, dim3(250), dim3(512), 0, stream,
                         hhd, wbf, bout, lb);
      hipLaunchKernelGGL(k_sum, dim3(256), dim3(256), 0, stream,
                         lb, wout, bout, hdst, emb, mq, sq, qbestV, qbestI,
                         xhi_c, xlo_c, (t < TT - 1) ? 1 : 0);
    }
    hipLaunchKernelGGL(k_fin, dim3(256), dim3(256), 0, stream,
                       lbuf + (size_t)((TT - 1) & 1) * BB * VV, mq, sq,
                       hrm + (size_t)BB * HH, out);
  } else {
    float* lb0 = lbuf;
    for (int t = 0; t < TT; ++t) {
      const int p = t & 1;
      const float* hsrc = hrm + (size_t)p * BB * HH;
      float* hdst = hrm + (size_t)(p ^ 1) * BB * HH;
      const unsigned short* hhs = hhi + (size_t)p * BB * HH;
      const unsigned short* hls = hlo + (size_t)p * BB * HH;
      unsigned short* hhd = hhi + (size_t)(p ^ 1) * BB * HH;
      unsigned short* hld = hlo + (size_t)(p ^ 1) * BB * HH;
      hipLaunchKernelGGL(k_gru_fb, dim3(768), dim3(64), 0, stream,
                         xhi0, xlo0, hhs, hls, wih, whh, gbuf);
      hipLaunchKernelGGL(k_gep_fb, dim3(256), dim3(256), 0, stream,
                         gbuf, bih, bhh, hsrc, hdst, hhd, hld);
      hipLaunchKernelGGL(k_logits_fb, dim3(500), dim3(256), 0, stream,
                         hhd, wout, bout, lb0);
      hipLaunchKernelGGL(k_sum, dim3(256), dim3(256), 0, stream,
                         lb0, wout, bout, hdst, emb, mq, sq, qbestV, qbestI,
                         xhi_c, xlo_c, (t < TT - 1) ? 1 : 0);
      hipLaunchKernelGGL(k_out_fb, dim3(256), dim3(256), 0, stream,
                         lb0, mq, sq, qbestV, qbestI, emb, hdst, out, xhi0, xlo0, t);
    }
  }
}